// Round 9
// baseline (167.883 us; speedup 1.0000x reference)
//
#include <hip/hip_runtime.h>
#include <cmath>

namespace {
constexpr int kN = 262144;           // samples (2^18)
constexpr int kL = 16;               // levels
constexpr int kT = 1 << 19;          // hash entries per level (power of 2)
constexpr unsigned kTMask = kT - 1;
constexpr int kB = 4096;             // sort buckets (16^3)

typedef __attribute__((ext_vector_type(8))) short short8;      // 8 bf16 (A/B frag)
typedef __attribute__((ext_vector_type(4))) float f32x4;       // C/D frag
typedef __attribute__((ext_vector_type(4))) unsigned short ushort4v;

struct Scales { float s[kL]; };

__device__ __forceinline__ unsigned short f2bf(float f) {
    unsigned u = __builtin_bit_cast(unsigned, f);
    return (unsigned short)((u + 0x7FFFu + ((u >> 16) & 1u)) >> 16);  // RNE
}

// ---------------------------------------------------------------------------
// Kernel 0: pre-swizzle MLP weights into per-lane MFMA B-fragment order, bf16.
// ---------------------------------------------------------------------------
__global__ __launch_bounds__(256) void prep_w(
    const float* __restrict__ w1, const float* __restrict__ w2,
    const float* __restrict__ w3, const float* __restrict__ w4,
    const float* __restrict__ w5, unsigned short* __restrict__ out)
{
    const int i = blockIdx.x * 256 + threadIdx.x;   // 0..10239
    const int f = i >> 9;
    const int l = (i >> 3) & 63;
    const int e = i & 7;
    const int cl = l & 15;
    const int kg = l >> 4;
    float v = 0.0f;
    if (f < 4) {                 // w1: [32][64]
        v = w1[(kg * 8 + e) * 64 + f * 16 + cl];
    } else if (f < 6) {          // w2: [64][16]
        const int q = f - 4;
        v = w2[(q * 32 + kg * 8 + e) * 16 + cl];
    } else if (f < 10) {         // w3: [32][64]
        v = w3[(kg * 8 + e) * 64 + (f - 6) * 16 + cl];
    } else if (f < 18) {         // w4: [64][64]
        const int g = f - 10, q = g >> 2, nt = g & 3;
        v = w4[(q * 32 + kg * 8 + e) * 64 + nt * 16 + cl];
    } else {                     // w5: [64][3] padded to 16 cols
        const int q = f - 18;
        v = (cl < 3) ? w5[(q * 32 + kg * 8 + e) * 3 + cl] : 0.0f;
    }
    out[i] = f2bf(v);
}

// ---------------------------------------------------------------------------
// Spatial bucketing (counting sort by 16^3 cell). Makes each encode wave's 64
// samples spatially adjacent so the TCP coalesces same-line gathers (R4/R8:
// gather wall = ~3 cy per DISTINCT line, independent of residency/occupancy).
// Within-bucket order is atomic-nondeterministic but per-sample results are
// bit-identical regardless of grouping, so final output is deterministic.
// ---------------------------------------------------------------------------
__global__ __launch_bounds__(256) void bucket_hist(
    const float* __restrict__ pos,
    unsigned short* __restrict__ key,
    unsigned* __restrict__ hist)
{
    const int n = blockIdx.x * 256 + threadIdx.x;
    const float px = (pos[n * 3 + 0] + 1.0f) * 0.5f;
    const float py = (pos[n * 3 + 1] + 1.0f) * 0.5f;
    const float pz = (pos[n * 3 + 2] + 1.0f) * 0.5f;
    const int cx = min(15, (int)(px * 16.0f));
    const int cy = min(15, (int)(py * 16.0f));
    const int cz = min(15, (int)(pz * 16.0f));
    const int k = (cx << 8) | (cy << 4) | cz;
    key[n] = (unsigned short)k;
    atomicAdd(&hist[k], 1u);
}

__global__ __launch_bounds__(1024) void bucket_scan(
    const unsigned* __restrict__ hist,
    unsigned* __restrict__ cursor)
{
    __shared__ unsigned s[1024];
    const int t = threadIdx.x;
    const unsigned v0 = hist[4 * t], v1 = hist[4 * t + 1];
    const unsigned v2 = hist[4 * t + 2], v3 = hist[4 * t + 3];
    const unsigned a0 = v0, a1 = a0 + v1, a2 = a1 + v2, a3 = a2 + v3;
    s[t] = a3;
    __syncthreads();
    for (int off = 1; off < 1024; off <<= 1) {
        unsigned x = 0;
        if (t >= off) x = s[t - off];
        __syncthreads();
        if (t >= off) s[t] += x;
        __syncthreads();
    }
    const unsigned base = (t > 0) ? s[t - 1] : 0u;
    cursor[4 * t]     = base;
    cursor[4 * t + 1] = base + a0;
    cursor[4 * t + 2] = base + a1;
    cursor[4 * t + 3] = base + a2;
}

__global__ __launch_bounds__(256) void bucket_scatter(
    const float* __restrict__ pos, const float* __restrict__ dir,
    const unsigned short* __restrict__ key,
    unsigned* __restrict__ cursor,
    float* __restrict__ spos, float* __restrict__ sdir,
    unsigned* __restrict__ s2o)
{
    const int n = blockIdx.x * 256 + threadIdx.x;
    const unsigned k = key[n];
    const unsigned i = atomicAdd(&cursor[k], 1u);
    s2o[i] = (unsigned)n;
    spos[i * 3 + 0] = pos[n * 3 + 0];
    spos[i * 3 + 1] = pos[n * 3 + 1];
    spos[i * 3 + 2] = pos[n * 3 + 2];
    sdir[i * 3 + 0] = dir[n * 3 + 0];
    sdir[i * 3 + 1] = dir[n * 3 + 1];
    sdir[i * 3 + 2] = dir[n * 3 + 2];
}

// ---------------------------------------------------------------------------
// Kernel 1: hash-grid encode in SORTED domain, 1 sample/thread, x-pair loads.
// Level block-uniform (bid>>10). Wave's 64 samples are spatially adjacent ->
// coarse/mid levels touch few unique lines -> TCP coalesces.
// ---------------------------------------------------------------------------
__global__ __launch_bounds__(256) void ngp_encode(
    const float* __restrict__ spos,
    const float2* __restrict__ table,
    unsigned* __restrict__ enc,
    Scales sc)
{
    const int bid = blockIdx.x;
    const int l = bid >> 10;                           // block-uniform level
    const int n = ((bid & 1023) << 8) | threadIdx.x;   // sorted-domain index

    const float s = sc.s[l];
    const float2* __restrict__ tl = table + (size_t)l * kT;

    const float px = (spos[n * 3 + 0] + 1.0f) * 0.5f;
    const float py = (spos[n * 3 + 1] + 1.0f) * 0.5f;
    const float pz = (spos[n * 3 + 2] + 1.0f) * 0.5f;
    const float sx = px * s, sy = py * s, sz = pz * s;
    const float fx = floorf(sx), fy = floorf(sy), fz = floorf(sz);
    const float rx = sx - fx, ry = sy - fy, rz = sz - fz;
    const unsigned cx = (unsigned)fx, cy = (unsigned)fy, cz = (unsigned)fz;

    const unsigned hy0 = cy * 2654435761u, hy1 = (cy + 1u) * 2654435761u;
    const unsigned hz0 = cz * 805459861u,  hz1 = (cz + 1u) * 805459861u;

    float4 pr[4];          // pair loads (both x-corners when cx even)
    float2 ex[4];          // extra loads for odd cx
    unsigned idx0v[4], hyzv[4];

    #pragma unroll
    for (int j = 0; j < 4; ++j) {              // j = oy*2 + oz
        const unsigned hyz = ((j >> 1) ? hy1 : hy0) ^ ((j & 1) ? hz1 : hz0);
        hyzv[j] = hyz;
        const unsigned idx0 = (cx ^ hyz) & kTMask;
        idx0v[j] = idx0;
        pr[j] = *reinterpret_cast<const float4*>(tl + (idx0 & ~1u));
    }

    if (cx & 1u) {
        const unsigned cx1 = cx + 1u;
        #pragma unroll
        for (int j = 0; j < 4; ++j)
            ex[j] = tl[(cx1 ^ hyzv[j]) & kTMask];
    }

    const bool odd = (cx & 1u) != 0u;
    const float wx0 = 1.0f - rx, wx1 = rx;
    float f0 = 0.f, f1 = 0.f;
    #pragma unroll
    for (int j = 0; j < 4; ++j) {
        const float wyz = ((j >> 1) ? ry : 1.0f - ry) *
                          ((j & 1) ? rz : 1.0f - rz);
        const bool hi = (idx0v[j] & 1u) != 0u;
        const float c0x = hi ? pr[j].z : pr[j].x;
        const float c0y = hi ? pr[j].w : pr[j].y;
        const float c1x = odd ? ex[j].x : (hi ? pr[j].x : pr[j].z);
        const float c1y = odd ? ex[j].y : (hi ? pr[j].y : pr[j].w);
        f0 = fmaf(c0x, wx0 * wyz, f0);
        f1 = fmaf(c0y, wx0 * wyz, f1);
        f0 = fmaf(c1x, wx1 * wyz, f0);
        f1 = fmaf(c1y, wx1 * wyz, f1);
    }
    enc[(size_t)l * kN + n] = (unsigned)f2bf(f0) | ((unsigned)f2bf(f1) << 16);
}

// ---------------------------------------------------------------------------
// Kernel 2: fully-fused MLP via MFMA, SORTED domain. 4 waves/block, 64
// samples/wave, wave-private LDS (no __syncthreads). Out scattered via s2o.
// ---------------------------------------------------------------------------
__global__ __launch_bounds__(256) void ngp_mlp_mfma(
    const unsigned* __restrict__ enc,
    const unsigned short* __restrict__ wbf,
    const float* __restrict__ sdir,
    const unsigned* __restrict__ s2o,
    const float* __restrict__ b1, const float* __restrict__ b2,
    const float* __restrict__ b3, const float* __restrict__ b4,
    const float* __restrict__ b5,
    float* __restrict__ out)
{
    __shared__ unsigned short sA[4][4096];   // 64k x 64s per wave
    __shared__ unsigned short sB[4][2048];   // 32k x 64s per wave

    const int tid = threadIdx.x;
    const int wid = tid >> 6;
    const int l   = tid & 63;
    const int cl  = l & 15;
    const int kg  = l >> 4;
    unsigned short* __restrict__ A_ = sA[wid];
    unsigned short* __restrict__ B_ = sB[wid];
    const int gbase = blockIdx.x * 256 + wid * 64;

    // ---- SH-16 for this lane's own sample, written to bufB k=16..31 ----
    {
        const int s = gbase + l;
        const float x = sdir[s * 3 + 0], y = sdir[s * 3 + 1], z = sdir[s * 3 + 2];
        const float xx = x * x, yy = y * y, zz = z * z;
        const float xy = x * y, yz = y * z, xz = x * z;
        float sh[16];
        sh[0] = 0.28209479177387814f;
        sh[1] = -0.48860251190291987f * y;
        sh[2] = 0.48860251190291987f * z;
        sh[3] = -0.48860251190291987f * x;
        sh[4] = 1.0925484305920792f * xy;
        sh[5] = -1.0925484305920792f * yz;
        sh[6] = 0.94617469575755997f * zz - 0.31539156525252005f;
        sh[7] = -1.0925484305920792f * xz;
        sh[8] = 0.54627421529603959f * (xx - yy);
        sh[9] = 0.59004358992664352f * y * (-3.0f * xx + yy);
        sh[10] = 2.8906114426405538f * xy * z;
        sh[11] = 0.45704579946446572f * y * (1.0f - 5.0f * zz);
        sh[12] = 0.3731763325901154f * z * (5.0f * zz - 3.0f);
        sh[13] = 0.45704579946446572f * x * (1.0f - 5.0f * zz);
        sh[14] = 1.445305721320277f * z * (xx - yy);
        sh[15] = 0.59004358992664352f * x * (xx - 3.0f * yy);
        #pragma unroll
        for (int j = 0; j < 16; ++j)
            B_[(l >> 4) * 512 + (16 + j) * 16 + (l & 15)] = f2bf(sh[j]);
    }

    // ---- Layer 1: enc(32) -> h1(64), relu ----
    short8 A1[4];
    #pragma unroll
    for (int m = 0; m < 4; ++m) {
        #pragma unroll
        for (int j = 0; j < 4; ++j) {
            const unsigned v = enc[(size_t)(kg * 4 + j) * kN + (gbase + m * 16 + cl)];
            A1[m][2 * j]     = (short)(v & 0xFFFFu);
            A1[m][2 * j + 1] = (short)(v >> 16);
        }
    }
    {
        short8 B1[4];
        #pragma unroll
        for (int nt = 0; nt < 4; ++nt)
            B1[nt] = *reinterpret_cast<const short8*>(&wbf[(size_t)(nt) * 512 + l * 8]);

        f32x4 acc[4][4];
        #pragma unroll
        for (int nt = 0; nt < 4; ++nt) {
            const float bv = b1[nt * 16 + cl];
            #pragma unroll
            for (int m = 0; m < 4; ++m) {
                acc[m][nt][0] = bv; acc[m][nt][1] = bv; acc[m][nt][2] = bv; acc[m][nt][3] = bv;
            }
        }
        #pragma unroll
        for (int m = 0; m < 4; ++m)
            #pragma unroll
            for (int nt = 0; nt < 4; ++nt)
                acc[m][nt] = __builtin_amdgcn_mfma_f32_16x16x32_bf16(A1[m], B1[nt], acc[m][nt], 0, 0, 0);

        #pragma unroll
        for (int m = 0; m < 4; ++m) {
            #pragma unroll
            for (int nt = 0; nt < 4; ++nt) {
                ushort4v pk;
                #pragma unroll
                for (int r = 0; r < 4; ++r) pk[r] = f2bf(fmaxf(acc[m][nt][r], 0.0f));
                *reinterpret_cast<ushort4v*>(&A_[m * 1024 + (nt * 16 + cl) * 16 + kg * 4]) = pk;
            }
        }
    }

    // ---- Layer 2: h1(64) -> h2(16), no relu; density = exp(h2[0]) ----
    {
        short8 A2[4][2];
        #pragma unroll
        for (int m = 0; m < 4; ++m)
            #pragma unroll
            for (int q = 0; q < 2; ++q)
                #pragma unroll
                for (int e = 0; e < 8; ++e)
                    A2[m][q][e] = (short)A_[m * 1024 + (q * 32 + kg * 8 + e) * 16 + cl];

        short8 B2[2];
        #pragma unroll
        for (int q = 0; q < 2; ++q)
            B2[q] = *reinterpret_cast<const short8*>(&wbf[(size_t)(4 + q) * 512 + l * 8]);

        f32x4 acc[4];
        const float bv = b2[cl];
        #pragma unroll
        for (int m = 0; m < 4; ++m) { acc[m][0] = bv; acc[m][1] = bv; acc[m][2] = bv; acc[m][3] = bv; }
        #pragma unroll
        for (int m = 0; m < 4; ++m)
            #pragma unroll
            for (int q = 0; q < 2; ++q)
                acc[m] = __builtin_amdgcn_mfma_f32_16x16x32_bf16(A2[m][q], B2[q], acc[m], 0, 0, 0);

        #pragma unroll
        for (int m = 0; m < 4; ++m) {
            if (cl == 0) {
                #pragma unroll
                for (int r = 0; r < 4; ++r)
                    out[(size_t)s2o[gbase + m * 16 + kg * 4 + r] * 4 + 0] = expf(acc[m][r]);
            }
            ushort4v pk;
            #pragma unroll
            for (int r = 0; r < 4; ++r) pk[r] = f2bf(acc[m][r]);
            *reinterpret_cast<ushort4v*>(&B_[m * 512 + cl * 16 + kg * 4]) = pk;
        }
    }

    // ---- Layer 3: [h2|SH](32) -> c1(64), relu ----
    {
        short8 A3[4];
        #pragma unroll
        for (int m = 0; m < 4; ++m)
            #pragma unroll
            for (int e = 0; e < 8; ++e)
                A3[m][e] = (short)B_[m * 512 + (kg * 8 + e) * 16 + cl];

        short8 B3[4];
        #pragma unroll
        for (int nt = 0; nt < 4; ++nt)
            B3[nt] = *reinterpret_cast<const short8*>(&wbf[(size_t)(6 + nt) * 512 + l * 8]);

        f32x4 acc[4][4];
        #pragma unroll
        for (int nt = 0; nt < 4; ++nt) {
            const float bv = b3[nt * 16 + cl];
            #pragma unroll
            for (int m = 0; m < 4; ++m) {
                acc[m][nt][0] = bv; acc[m][nt][1] = bv; acc[m][nt][2] = bv; acc[m][nt][3] = bv;
            }
        }
        #pragma unroll
        for (int m = 0; m < 4; ++m)
            #pragma unroll
            for (int nt = 0; nt < 4; ++nt)
                acc[m][nt] = __builtin_amdgcn_mfma_f32_16x16x32_bf16(A3[m], B3[nt], acc[m][nt], 0, 0, 0);

        #pragma unroll
        for (int m = 0; m < 4; ++m) {
            #pragma unroll
            for (int nt = 0; nt < 4; ++nt) {
                ushort4v pk;
                #pragma unroll
                for (int r = 0; r < 4; ++r) pk[r] = f2bf(fmaxf(acc[m][nt][r], 0.0f));
                *reinterpret_cast<ushort4v*>(&A_[m * 1024 + (nt * 16 + cl) * 16 + kg * 4]) = pk;
            }
        }
    }

    // ---- Layer 4: c1(64) -> c2(64), relu ----
    {
        short8 A4[4][2];
        #pragma unroll
        for (int m = 0; m < 4; ++m)
            #pragma unroll
            for (int q = 0; q < 2; ++q)
                #pragma unroll
                for (int e = 0; e < 8; ++e)
                    A4[m][q][e] = (short)A_[m * 1024 + (q * 32 + kg * 8 + e) * 16 + cl];

        short8 B4[2][4];
        #pragma unroll
        for (int q = 0; q < 2; ++q)
            #pragma unroll
            for (int nt = 0; nt < 4; ++nt)
                B4[q][nt] = *reinterpret_cast<const short8*>(&wbf[(size_t)(10 + q * 4 + nt) * 512 + l * 8]);

        f32x4 acc[4][4];
        #pragma unroll
        for (int nt = 0; nt < 4; ++nt) {
            const float bv = b4[nt * 16 + cl];
            #pragma unroll
            for (int m = 0; m < 4; ++m) {
                acc[m][nt][0] = bv; acc[m][nt][1] = bv; acc[m][nt][2] = bv; acc[m][nt][3] = bv;
            }
        }
        #pragma unroll
        for (int m = 0; m < 4; ++m)
            #pragma unroll
            for (int nt = 0; nt < 4; ++nt)
                #pragma unroll
                for (int q = 0; q < 2; ++q)
                    acc[m][nt] = __builtin_amdgcn_mfma_f32_16x16x32_bf16(A4[m][q], B4[q][nt], acc[m][nt], 0, 0, 0);

        #pragma unroll
        for (int m = 0; m < 4; ++m) {
            #pragma unroll
            for (int nt = 0; nt < 4; ++nt) {
                ushort4v pk;
                #pragma unroll
                for (int r = 0; r < 4; ++r) pk[r] = f2bf(fmaxf(acc[m][nt][r], 0.0f));
                *reinterpret_cast<ushort4v*>(&A_[m * 1024 + (nt * 16 + cl) * 16 + kg * 4]) = pk;
            }
        }
    }

    // ---- Layer 5: c2(64) -> 3, sigmoid ----
    {
        short8 A5[4][2];
        #pragma unroll
        for (int m = 0; m < 4; ++m)
            #pragma unroll
            for (int q = 0; q < 2; ++q)
                #pragma unroll
                for (int e = 0; e < 8; ++e)
                    A5[m][q][e] = (short)A_[m * 1024 + (q * 32 + kg * 8 + e) * 16 + cl];

        short8 B5[2];
        #pragma unroll
        for (int q = 0; q < 2; ++q)
            B5[q] = *reinterpret_cast<const short8*>(&wbf[(size_t)(18 + q) * 512 + l * 8]);

        f32x4 acc[4];
        const float bv = (cl < 3) ? b5[cl] : 0.0f;
        #pragma unroll
        for (int m = 0; m < 4; ++m) { acc[m][0] = bv; acc[m][1] = bv; acc[m][2] = bv; acc[m][3] = bv; }
        #pragma unroll
        for (int m = 0; m < 4; ++m)
            #pragma unroll
            for (int q = 0; q < 2; ++q)
                acc[m] = __builtin_amdgcn_mfma_f32_16x16x32_bf16(A5[m][q], B5[q], acc[m], 0, 0, 0);

        if (cl < 3) {
            #pragma unroll
            for (int m = 0; m < 4; ++m)
                #pragma unroll
                for (int r = 0; r < 4; ++r)
                    out[(size_t)s2o[gbase + m * 16 + kg * 4 + r] * 4 + 1 + cl] =
                        1.0f / (1.0f + expf(-acc[m][r]));
        }
    }
}

} // namespace

extern "C" void kernel_launch(void* const* d_in, const int* in_sizes, int n_in,
                              void* d_out, int out_size, void* d_ws, size_t ws_size,
                              hipStream_t stream) {
    (void)in_sizes; (void)n_in; (void)out_size; (void)ws_size;

    Scales sc;
    const double g = exp((log(2048.0) - log(16.0)) / 15.0);
    for (int l = 0; l < kL; ++l) sc.s[l] = (float)floor(16.0 * pow(g, (double)l));

    const float*  pos   = (const float*)d_in[0];
    const float*  dir   = (const float*)d_in[1];
    const float2* table = (const float2*)d_in[2];
    const float *w1 = (const float*)d_in[3],  *b1 = (const float*)d_in[4];
    const float *w2 = (const float*)d_in[5],  *b2 = (const float*)d_in[6];
    const float *w3 = (const float*)d_in[7],  *b3 = (const float*)d_in[8];
    const float *w4 = (const float*)d_in[9],  *b4 = (const float*)d_in[10];
    const float *w5 = (const float*)d_in[11], *b5 = (const float*)d_in[12];
    float* out = (float*)d_out;

    // ws layout (bytes):
    char* ws = (char*)d_ws;
    unsigned short* wbf   = (unsigned short*)(ws);              // 40960 B
    unsigned*       hist  = (unsigned*)(ws + 65536);            // 16384 B
    unsigned*       cursor= (unsigned*)(ws + 81920);            // 16384 B
    unsigned short* key   = (unsigned short*)(ws + 98304);      // 524288 B
    unsigned*       s2o   = (unsigned*)(ws + 622592);           // 1 MB
    float*          spos  = (float*)(ws + 1671168);             // 3 MB
    float*          sdir  = (float*)(ws + 4816896);             // 3 MB
    unsigned*       enc   = (unsigned*)(ws + 7962624);          // 16.8 MB

    hipMemsetAsync(hist, 0, kB * sizeof(unsigned), stream);
    prep_w<<<40, 256, 0, stream>>>(w1, w2, w3, w4, w5, wbf);
    bucket_hist<<<kN / 256, 256, 0, stream>>>(pos, key, hist);
    bucket_scan<<<1, 1024, 0, stream>>>(hist, cursor);
    bucket_scatter<<<kN / 256, 256, 0, stream>>>(pos, dir, key, cursor, spos, sdir, s2o);
    ngp_encode<<<kL * 1024, 256, 0, stream>>>(spos, table, enc, sc);
    ngp_mlp_mfma<<<kN / 256, 256, 0, stream>>>(enc, wbf, sdir, s2o,
        b1, b2, b3, b4, b5, out);
}

// Round 10
// 164.946 us; speedup vs baseline: 1.0178x; 1.0178x over previous
//
#include <hip/hip_runtime.h>
#include <cmath>

namespace {
constexpr int kN = 262144;           // samples (2^18)
constexpr int kL = 16;               // levels
constexpr int kT = 1 << 19;          // hash entries per level (power of 2)
constexpr unsigned kTMask = kT - 1;
constexpr int kB = 32768;            // sort buckets (32^3, Morton)

typedef __attribute__((ext_vector_type(8))) short short8;      // 8 bf16 (A/B frag)
typedef __attribute__((ext_vector_type(4))) float f32x4;       // C/D frag
typedef __attribute__((ext_vector_type(4))) unsigned short ushort4v;

struct Scales { float s[kL]; };

__device__ __forceinline__ unsigned short f2bf(float f) {
    unsigned u = __builtin_bit_cast(unsigned, f);
    return (unsigned short)((u + 0x7FFFu + ((u >> 16) & 1u)) >> 16);  // RNE
}

__device__ __forceinline__ unsigned morton5(unsigned x) {
    // spread 5 bits to every 3rd bit: b4..b0 -> bits 12,9,6,3,0
    x &= 31u;
    x = (x | (x << 8)) & 0x100Fu;
    x = (x | (x << 4)) & 0x10C3u;
    x = (x | (x << 2)) & 0x1249u;
    return x;
}

// ---------------------------------------------------------------------------
// Kernel 0: pre-swizzle MLP weights into per-lane MFMA B-fragment order, bf16.
// ---------------------------------------------------------------------------
__global__ __launch_bounds__(256) void prep_w(
    const float* __restrict__ w1, const float* __restrict__ w2,
    const float* __restrict__ w3, const float* __restrict__ w4,
    const float* __restrict__ w5, unsigned short* __restrict__ out)
{
    const int i = blockIdx.x * 256 + threadIdx.x;   // 0..10239
    const int f = i >> 9;
    const int l = (i >> 3) & 63;
    const int e = i & 7;
    const int cl = l & 15;
    const int kg = l >> 4;
    float v = 0.0f;
    if (f < 4) {                 // w1: [32][64]
        v = w1[(kg * 8 + e) * 64 + f * 16 + cl];
    } else if (f < 6) {          // w2: [64][16]
        const int q = f - 4;
        v = w2[(q * 32 + kg * 8 + e) * 16 + cl];
    } else if (f < 10) {         // w3: [32][64]
        v = w3[(kg * 8 + e) * 64 + (f - 6) * 16 + cl];
    } else if (f < 18) {         // w4: [64][64]
        const int g = f - 10, q = g >> 2, nt = g & 3;
        v = w4[(q * 32 + kg * 8 + e) * 64 + nt * 16 + cl];
    } else {                     // w5: [64][3] padded to 16 cols
        const int q = f - 18;
        v = (cl < 3) ? w5[(q * 32 + kg * 8 + e) * 3 + cl] : 0.0f;
    }
    out[i] = f2bf(v);
}

// ---------------------------------------------------------------------------
// Spatial bucketing: counting sort by 32^3 Morton cell. Makes each encode
// wave's 64 samples a compact spatial block so the TCP coalesces same-line
// gathers (R8/R9 fit: cost = 0.5cy/lane-addr + 2.55cy/distinct-line).
// 32768 cells = 2048 histogram lines -> ~128 serialized atomics/line (8x less
// than 4096 cells). Within-bucket order is atomic-nondeterministic but each
// sample's result is independent of grouping -> output deterministic.
// ---------------------------------------------------------------------------
__global__ __launch_bounds__(256) void bucket_hist(
    const float* __restrict__ pos,
    unsigned short* __restrict__ key,
    unsigned* __restrict__ hist)
{
    const int n = blockIdx.x * 256 + threadIdx.x;
    const float px = (pos[n * 3 + 0] + 1.0f) * 0.5f;
    const float py = (pos[n * 3 + 1] + 1.0f) * 0.5f;
    const float pz = (pos[n * 3 + 2] + 1.0f) * 0.5f;
    const unsigned cx = (unsigned)min(31, (int)(px * 32.0f));
    const unsigned cy = (unsigned)min(31, (int)(py * 32.0f));
    const unsigned cz = (unsigned)min(31, (int)(pz * 32.0f));
    const unsigned k = morton5(cx) | (morton5(cy) << 1) | (morton5(cz) << 2);
    key[n] = (unsigned short)k;
    atomicAdd(&hist[k], 1u);
}

__global__ __launch_bounds__(1024) void bucket_scan(
    const unsigned* __restrict__ hist,
    unsigned* __restrict__ cursor)
{
    __shared__ unsigned s[1024];
    const int t = threadIdx.x;
    unsigned sum = 0;
    #pragma unroll 4
    for (int i = 0; i < 32; ++i) sum += hist[t * 32 + i];
    s[t] = sum;
    __syncthreads();
    for (int off = 1; off < 1024; off <<= 1) {
        unsigned x = (t >= off) ? s[t - off] : 0u;
        __syncthreads();
        s[t] += x;
        __syncthreads();
    }
    unsigned base = (t > 0) ? s[t - 1] : 0u;
    #pragma unroll 4
    for (int i = 0; i < 32; ++i) {
        const unsigned h = hist[t * 32 + i];
        cursor[t * 32 + i] = base;
        base += h;
    }
}

__global__ __launch_bounds__(256) void bucket_scatter(
    const float* __restrict__ pos,
    const unsigned short* __restrict__ key,
    unsigned* __restrict__ cursor,
    float4* __restrict__ spos4,
    unsigned* __restrict__ s2o)
{
    const int n = blockIdx.x * 256 + threadIdx.x;
    const unsigned k = key[n];
    const unsigned i = atomicAdd(&cursor[k], 1u);
    spos4[i] = make_float4(pos[n * 3 + 0], pos[n * 3 + 1], pos[n * 3 + 2],
                           __uint_as_float((unsigned)n));
    s2o[i] = (unsigned)n;
}

// ---------------------------------------------------------------------------
// Kernel 1: hash-grid encode in SORTED domain, 1 sample/thread, x-pair loads.
// Level block-uniform (bid>>10). Wave's 64 samples are a compact Morton block.
// ---------------------------------------------------------------------------
__global__ __launch_bounds__(256) void ngp_encode(
    const float4* __restrict__ spos4,
    const float2* __restrict__ table,
    unsigned* __restrict__ enc,
    Scales sc)
{
    const int bid = blockIdx.x;
    const int l = bid >> 10;                           // block-uniform level
    const int n = ((bid & 1023) << 8) | threadIdx.x;   // sorted-domain index

    const float s = sc.s[l];
    const float2* __restrict__ tl = table + (size_t)l * kT;

    const float4 p4 = spos4[n];
    const float px = (p4.x + 1.0f) * 0.5f;
    const float py = (p4.y + 1.0f) * 0.5f;
    const float pz = (p4.z + 1.0f) * 0.5f;
    const float sx = px * s, sy = py * s, sz = pz * s;
    const float fx = floorf(sx), fy = floorf(sy), fz = floorf(sz);
    const float rx = sx - fx, ry = sy - fy, rz = sz - fz;
    const unsigned cx = (unsigned)fx, cy = (unsigned)fy, cz = (unsigned)fz;

    const unsigned hy0 = cy * 2654435761u, hy1 = (cy + 1u) * 2654435761u;
    const unsigned hz0 = cz * 805459861u,  hz1 = (cz + 1u) * 805459861u;

    float4 pr[4];          // pair loads (both x-corners when cx even)
    float2 ex[4];          // extra loads for odd cx
    unsigned idx0v[4], hyzv[4];

    #pragma unroll
    for (int j = 0; j < 4; ++j) {              // j = oy*2 + oz
        const unsigned hyz = ((j >> 1) ? hy1 : hy0) ^ ((j & 1) ? hz1 : hz0);
        hyzv[j] = hyz;
        const unsigned idx0 = (cx ^ hyz) & kTMask;
        idx0v[j] = idx0;
        pr[j] = *reinterpret_cast<const float4*>(tl + (idx0 & ~1u));
    }

    if (cx & 1u) {
        const unsigned cx1 = cx + 1u;
        #pragma unroll
        for (int j = 0; j < 4; ++j)
            ex[j] = tl[(cx1 ^ hyzv[j]) & kTMask];
    }

    const bool odd = (cx & 1u) != 0u;
    const float wx0 = 1.0f - rx, wx1 = rx;
    float f0 = 0.f, f1 = 0.f;
    #pragma unroll
    for (int j = 0; j < 4; ++j) {
        const float wyz = ((j >> 1) ? ry : 1.0f - ry) *
                          ((j & 1) ? rz : 1.0f - rz);
        const bool hi = (idx0v[j] & 1u) != 0u;
        const float c0x = hi ? pr[j].z : pr[j].x;
        const float c0y = hi ? pr[j].w : pr[j].y;
        const float c1x = odd ? ex[j].x : (hi ? pr[j].x : pr[j].z);
        const float c1y = odd ? ex[j].y : (hi ? pr[j].y : pr[j].w);
        f0 = fmaf(c0x, wx0 * wyz, f0);
        f1 = fmaf(c0y, wx0 * wyz, f1);
        f0 = fmaf(c1x, wx1 * wyz, f0);
        f1 = fmaf(c1y, wx1 * wyz, f1);
    }
    enc[(size_t)l * kN + n] = (unsigned)f2bf(f0) | ((unsigned)f2bf(f1) << 16);
}

// ---------------------------------------------------------------------------
// Kernel 2: fully-fused MLP via MFMA, SORTED domain. 4 waves/block, 64
// samples/wave, wave-private LDS (no __syncthreads). dir gathered and out
// scattered through s2o.
// ---------------------------------------------------------------------------
__global__ __launch_bounds__(256) void ngp_mlp_mfma(
    const unsigned* __restrict__ enc,
    const unsigned short* __restrict__ wbf,
    const float* __restrict__ dir,
    const unsigned* __restrict__ s2o,
    const float* __restrict__ b1, const float* __restrict__ b2,
    const float* __restrict__ b3, const float* __restrict__ b4,
    const float* __restrict__ b5,
    float* __restrict__ out)
{
    __shared__ unsigned short sA[4][4096];   // 64k x 64s per wave
    __shared__ unsigned short sB[4][2048];   // 32k x 64s per wave

    const int tid = threadIdx.x;
    const int wid = tid >> 6;
    const int l   = tid & 63;
    const int cl  = l & 15;
    const int kg  = l >> 4;
    unsigned short* __restrict__ A_ = sA[wid];
    unsigned short* __restrict__ B_ = sB[wid];
    const int gbase = blockIdx.x * 256 + wid * 64;

    // ---- SH-16 for this lane's own sample (dir gathered via s2o) ----
    {
        const unsigned n = s2o[gbase + l];
        const float x = dir[n * 3 + 0], y = dir[n * 3 + 1], z = dir[n * 3 + 2];
        const float xx = x * x, yy = y * y, zz = z * z;
        const float xy = x * y, yz = y * z, xz = x * z;
        float sh[16];
        sh[0] = 0.28209479177387814f;
        sh[1] = -0.48860251190291987f * y;
        sh[2] = 0.48860251190291987f * z;
        sh[3] = -0.48860251190291987f * x;
        sh[4] = 1.0925484305920792f * xy;
        sh[5] = -1.0925484305920792f * yz;
        sh[6] = 0.94617469575755997f * zz - 0.31539156525252005f;
        sh[7] = -1.0925484305920792f * xz;
        sh[8] = 0.54627421529603959f * (xx - yy);
        sh[9] = 0.59004358992664352f * y * (-3.0f * xx + yy);
        sh[10] = 2.8906114426405538f * xy * z;
        sh[11] = 0.45704579946446572f * y * (1.0f - 5.0f * zz);
        sh[12] = 0.3731763325901154f * z * (5.0f * zz - 3.0f);
        sh[13] = 0.45704579946446572f * x * (1.0f - 5.0f * zz);
        sh[14] = 1.445305721320277f * z * (xx - yy);
        sh[15] = 0.59004358992664352f * x * (xx - 3.0f * yy);
        #pragma unroll
        for (int j = 0; j < 16; ++j)
            B_[(l >> 4) * 512 + (16 + j) * 16 + (l & 15)] = f2bf(sh[j]);
    }

    // ---- Layer 1: enc(32) -> h1(64), relu ----
    short8 A1[4];
    #pragma unroll
    for (int m = 0; m < 4; ++m) {
        #pragma unroll
        for (int j = 0; j < 4; ++j) {
            const unsigned v = enc[(size_t)(kg * 4 + j) * kN + (gbase + m * 16 + cl)];
            A1[m][2 * j]     = (short)(v & 0xFFFFu);
            A1[m][2 * j + 1] = (short)(v >> 16);
        }
    }
    {
        short8 B1[4];
        #pragma unroll
        for (int nt = 0; nt < 4; ++nt)
            B1[nt] = *reinterpret_cast<const short8*>(&wbf[(size_t)(nt) * 512 + l * 8]);

        f32x4 acc[4][4];
        #pragma unroll
        for (int nt = 0; nt < 4; ++nt) {
            const float bv = b1[nt * 16 + cl];
            #pragma unroll
            for (int m = 0; m < 4; ++m) {
                acc[m][nt][0] = bv; acc[m][nt][1] = bv; acc[m][nt][2] = bv; acc[m][nt][3] = bv;
            }
        }
        #pragma unroll
        for (int m = 0; m < 4; ++m)
            #pragma unroll
            for (int nt = 0; nt < 4; ++nt)
                acc[m][nt] = __builtin_amdgcn_mfma_f32_16x16x32_bf16(A1[m], B1[nt], acc[m][nt], 0, 0, 0);

        #pragma unroll
        for (int m = 0; m < 4; ++m) {
            #pragma unroll
            for (int nt = 0; nt < 4; ++nt) {
                ushort4v pk;
                #pragma unroll
                for (int r = 0; r < 4; ++r) pk[r] = f2bf(fmaxf(acc[m][nt][r], 0.0f));
                *reinterpret_cast<ushort4v*>(&A_[m * 1024 + (nt * 16 + cl) * 16 + kg * 4]) = pk;
            }
        }
    }

    // ---- Layer 2: h1(64) -> h2(16), no relu; density = exp(h2[0]) ----
    {
        short8 A2[4][2];
        #pragma unroll
        for (int m = 0; m < 4; ++m)
            #pragma unroll
            for (int q = 0; q < 2; ++q)
                #pragma unroll
                for (int e = 0; e < 8; ++e)
                    A2[m][q][e] = (short)A_[m * 1024 + (q * 32 + kg * 8 + e) * 16 + cl];

        short8 B2[2];
        #pragma unroll
        for (int q = 0; q < 2; ++q)
            B2[q] = *reinterpret_cast<const short8*>(&wbf[(size_t)(4 + q) * 512 + l * 8]);

        f32x4 acc[4];
        const float bv = b2[cl];
        #pragma unroll
        for (int m = 0; m < 4; ++m) { acc[m][0] = bv; acc[m][1] = bv; acc[m][2] = bv; acc[m][3] = bv; }
        #pragma unroll
        for (int m = 0; m < 4; ++m)
            #pragma unroll
            for (int q = 0; q < 2; ++q)
                acc[m] = __builtin_amdgcn_mfma_f32_16x16x32_bf16(A2[m][q], B2[q], acc[m], 0, 0, 0);

        #pragma unroll
        for (int m = 0; m < 4; ++m) {
            if (cl == 0) {
                #pragma unroll
                for (int r = 0; r < 4; ++r)
                    out[(size_t)s2o[gbase + m * 16 + kg * 4 + r] * 4 + 0] = expf(acc[m][r]);
            }
            ushort4v pk;
            #pragma unroll
            for (int r = 0; r < 4; ++r) pk[r] = f2bf(acc[m][r]);
            *reinterpret_cast<ushort4v*>(&B_[m * 512 + cl * 16 + kg * 4]) = pk;
        }
    }

    // ---- Layer 3: [h2|SH](32) -> c1(64), relu ----
    {
        short8 A3[4];
        #pragma unroll
        for (int m = 0; m < 4; ++m)
            #pragma unroll
            for (int e = 0; e < 8; ++e)
                A3[m][e] = (short)B_[m * 512 + (kg * 8 + e) * 16 + cl];

        short8 B3[4];
        #pragma unroll
        for (int nt = 0; nt < 4; ++nt)
            B3[nt] = *reinterpret_cast<const short8*>(&wbf[(size_t)(6 + nt) * 512 + l * 8]);

        f32x4 acc[4][4];
        #pragma unroll
        for (int nt = 0; nt < 4; ++nt) {
            const float bv = b3[nt * 16 + cl];
            #pragma unroll
            for (int m = 0; m < 4; ++m) {
                acc[m][nt][0] = bv; acc[m][nt][1] = bv; acc[m][nt][2] = bv; acc[m][nt][3] = bv;
            }
        }
        #pragma unroll
        for (int m = 0; m < 4; ++m)
            #pragma unroll
            for (int nt = 0; nt < 4; ++nt)
                acc[m][nt] = __builtin_amdgcn_mfma_f32_16x16x32_bf16(A3[m], B3[nt], acc[m][nt], 0, 0, 0);

        #pragma unroll
        for (int m = 0; m < 4; ++m) {
            #pragma unroll
            for (int nt = 0; nt < 4; ++nt) {
                ushort4v pk;
                #pragma unroll
                for (int r = 0; r < 4; ++r) pk[r] = f2bf(fmaxf(acc[m][nt][r], 0.0f));
                *reinterpret_cast<ushort4v*>(&A_[m * 1024 + (nt * 16 + cl) * 16 + kg * 4]) = pk;
            }
        }
    }

    // ---- Layer 4: c1(64) -> c2(64), relu ----
    {
        short8 A4[4][2];
        #pragma unroll
        for (int m = 0; m < 4; ++m)
            #pragma unroll
            for (int q = 0; q < 2; ++q)
                #pragma unroll
                for (int e = 0; e < 8; ++e)
                    A4[m][q][e] = (short)A_[m * 1024 + (q * 32 + kg * 8 + e) * 16 + cl];

        short8 B4[2][4];
        #pragma unroll
        for (int q = 0; q < 2; ++q)
            #pragma unroll
            for (int nt = 0; nt < 4; ++nt)
                B4[q][nt] = *reinterpret_cast<const short8*>(&wbf[(size_t)(10 + q * 4 + nt) * 512 + l * 8]);

        f32x4 acc[4][4];
        #pragma unroll
        for (int nt = 0; nt < 4; ++nt) {
            const float bv = b4[nt * 16 + cl];
            #pragma unroll
            for (int m = 0; m < 4; ++m) {
                acc[m][nt][0] = bv; acc[m][nt][1] = bv; acc[m][nt][2] = bv; acc[m][nt][3] = bv;
            }
        }
        #pragma unroll
        for (int m = 0; m < 4; ++m)
            #pragma unroll
            for (int nt = 0; nt < 4; ++nt)
                #pragma unroll
                for (int q = 0; q < 2; ++q)
                    acc[m][nt] = __builtin_amdgcn_mfma_f32_16x16x32_bf16(A4[m][q], B4[q][nt], acc[m][nt], 0, 0, 0);

        #pragma unroll
        for (int m = 0; m < 4; ++m) {
            #pragma unroll
            for (int nt = 0; nt < 4; ++nt) {
                ushort4v pk;
                #pragma unroll
                for (int r = 0; r < 4; ++r) pk[r] = f2bf(fmaxf(acc[m][nt][r], 0.0f));
                *reinterpret_cast<ushort4v*>(&A_[m * 1024 + (nt * 16 + cl) * 16 + kg * 4]) = pk;
            }
        }
    }

    // ---- Layer 5: c2(64) -> 3, sigmoid ----
    {
        short8 A5[4][2];
        #pragma unroll
        for (int m = 0; m < 4; ++m)
            #pragma unroll
            for (int q = 0; q < 2; ++q)
                #pragma unroll
                for (int e = 0; e < 8; ++e)
                    A5[m][q][e] = (short)A_[m * 1024 + (q * 32 + kg * 8 + e) * 16 + cl];

        short8 B5[2];
        #pragma unroll
        for (int q = 0; q < 2; ++q)
            B5[q] = *reinterpret_cast<const short8*>(&wbf[(size_t)(18 + q) * 512 + l * 8]);

        f32x4 acc[4];
        const float bv = (cl < 3) ? b5[cl] : 0.0f;
        #pragma unroll
        for (int m = 0; m < 4; ++m) { acc[m][0] = bv; acc[m][1] = bv; acc[m][2] = bv; acc[m][3] = bv; }
        #pragma unroll
        for (int m = 0; m < 4; ++m)
            #pragma unroll
            for (int q = 0; q < 2; ++q)
                acc[m] = __builtin_amdgcn_mfma_f32_16x16x32_bf16(A5[m][q], B5[q], acc[m], 0, 0, 0);

        if (cl < 3) {
            #pragma unroll
            for (int m = 0; m < 4; ++m)
                #pragma unroll
                for (int r = 0; r < 4; ++r)
                    out[(size_t)s2o[gbase + m * 16 + kg * 4 + r] * 4 + 1 + cl] =
                        1.0f / (1.0f + expf(-acc[m][r]));
        }
    }
}

} // namespace

extern "C" void kernel_launch(void* const* d_in, const int* in_sizes, int n_in,
                              void* d_out, int out_size, void* d_ws, size_t ws_size,
                              hipStream_t stream) {
    (void)in_sizes; (void)n_in; (void)out_size; (void)ws_size;

    Scales sc;
    const double g = exp((log(2048.0) - log(16.0)) / 15.0);
    for (int l = 0; l < kL; ++l) sc.s[l] = (float)floor(16.0 * pow(g, (double)l));

    const float*  pos   = (const float*)d_in[0];
    const float*  dir   = (const float*)d_in[1];
    const float2* table = (const float2*)d_in[2];
    const float *w1 = (const float*)d_in[3],  *b1 = (const float*)d_in[4];
    const float *w2 = (const float*)d_in[5],  *b2 = (const float*)d_in[6];
    const float *w3 = (const float*)d_in[7],  *b3 = (const float*)d_in[8];
    const float *w4 = (const float*)d_in[9],  *b4 = (const float*)d_in[10];
    const float *w5 = (const float*)d_in[11], *b5 = (const float*)d_in[12];
    float* out = (float*)d_out;

    // ws layout (bytes):
    char* ws = (char*)d_ws;
    unsigned short* wbf    = (unsigned short*)(ws);             // 40960 B
    unsigned*       hist   = (unsigned*)(ws + 65536);           // 131072 B
    unsigned*       cursor = (unsigned*)(ws + 196608);          // 131072 B
    unsigned short* key    = (unsigned short*)(ws + 327680);    // 524288 B
    unsigned*       s2o    = (unsigned*)(ws + 851968);          // 1 MB
    float4*         spos4  = (float4*)(ws + 1966080);           // 4 MB
    unsigned*       enc    = (unsigned*)(ws + 6291456);         // 16.8 MB

    hipMemsetAsync(hist, 0, kB * sizeof(unsigned), stream);
    prep_w<<<40, 256, 0, stream>>>(w1, w2, w3, w4, w5, wbf);
    bucket_hist<<<kN / 256, 256, 0, stream>>>(pos, key, hist);
    bucket_scan<<<1, 1024, 0, stream>>>(hist, cursor);
    bucket_scatter<<<kN / 256, 256, 0, stream>>>(pos, key, cursor, spos4, s2o);
    ngp_encode<<<kL * 1024, 256, 0, stream>>>(spos4, table, enc, sc);
    ngp_mlp_mfma<<<kN / 256, 256, 0, stream>>>(enc, wbf, dir, s2o,
        b1, b2, b3, b4, b5, out);
}

// Round 11
// 155.034 us; speedup vs baseline: 1.0829x; 1.0639x over previous
//
#include <hip/hip_runtime.h>
#include <cmath>

namespace {
constexpr int kN = 262144;           // samples (2^18)
constexpr int kL = 16;               // levels
constexpr int kT = 1 << 19;          // hash entries per level (power of 2)
constexpr unsigned kTMask = kT - 1;
constexpr int kB = 32768;            // sort buckets (32^3, Morton)

typedef __attribute__((ext_vector_type(8))) short short8;      // 8 bf16 (A/B frag)
typedef __attribute__((ext_vector_type(4))) float f32x4;       // C/D frag
typedef __attribute__((ext_vector_type(4))) unsigned short ushort4v;

struct Scales { float s[kL]; };

__device__ __forceinline__ unsigned short f2bf(float f) {
    unsigned u = __builtin_bit_cast(unsigned, f);
    return (unsigned short)((u + 0x7FFFu + ((u >> 16) & 1u)) >> 16);  // RNE
}

__device__ __forceinline__ unsigned morton5(unsigned x) {
    x &= 31u;
    x = (x | (x << 8)) & 0x100Fu;
    x = (x | (x << 4)) & 0x10C3u;
    x = (x | (x << 2)) & 0x1249u;
    return x;
}

// ---------------------------------------------------------------------------
// Kernel 0: pre-swizzle MLP weights into per-lane MFMA B-fragment order, bf16.
// ---------------------------------------------------------------------------
__global__ __launch_bounds__(256) void prep_w(
    const float* __restrict__ w1, const float* __restrict__ w2,
    const float* __restrict__ w3, const float* __restrict__ w4,
    const float* __restrict__ w5, unsigned short* __restrict__ out)
{
    const int i = blockIdx.x * 256 + threadIdx.x;   // 0..10239
    const int f = i >> 9;
    const int l = (i >> 3) & 63;
    const int e = i & 7;
    const int cl = l & 15;
    const int kg = l >> 4;
    float v = 0.0f;
    if (f < 4) {                 // w1: [32][64]
        v = w1[(kg * 8 + e) * 64 + f * 16 + cl];
    } else if (f < 6) {          // w2: [64][16]
        const int q = f - 4;
        v = w2[(q * 32 + kg * 8 + e) * 16 + cl];
    } else if (f < 10) {         // w3: [32][64]
        v = w3[(kg * 8 + e) * 64 + (f - 6) * 16 + cl];
    } else if (f < 18) {         // w4: [64][64]
        const int g = f - 10, q = g >> 2, nt = g & 3;
        v = w4[(q * 32 + kg * 8 + e) * 64 + nt * 16 + cl];
    } else {                     // w5: [64][3] padded to 16 cols
        const int q = f - 18;
        v = (cl < 3) ? w5[(q * 32 + kg * 8 + e) * 3 + cl] : 0.0f;
    }
    out[i] = f2bf(v);
}

// ---------------------------------------------------------------------------
// Spatial bucketing: counting sort by 32^3 Morton cell (see R9/R10 notes).
// R10 post-mortem: the single-block scan with transposed reads cost ~35us on
// one CU (32k line-touches). Replaced by a 3-pass parallel COALESCED scan.
// ---------------------------------------------------------------------------
__global__ __launch_bounds__(256) void bucket_hist(
    const float* __restrict__ pos,
    unsigned short* __restrict__ key,
    unsigned* __restrict__ hist)
{
    const int n = blockIdx.x * 256 + threadIdx.x;
    const float px = (pos[n * 3 + 0] + 1.0f) * 0.5f;
    const float py = (pos[n * 3 + 1] + 1.0f) * 0.5f;
    const float pz = (pos[n * 3 + 2] + 1.0f) * 0.5f;
    const unsigned cx = (unsigned)min(31, (int)(px * 32.0f));
    const unsigned cy = (unsigned)min(31, (int)(py * 32.0f));
    const unsigned cz = (unsigned)min(31, (int)(pz * 32.0f));
    const unsigned k = morton5(cx) | (morton5(cy) << 1) | (morton5(cz) << 2);
    key[n] = (unsigned short)k;
    atomicAdd(&hist[k], 1u);
}

// scanA: partial[b] = sum of hist[b*256 .. b*256+255]  (coalesced)
__global__ __launch_bounds__(256) void scan_partial(
    const unsigned* __restrict__ hist,
    unsigned* __restrict__ partial)
{
    __shared__ unsigned s[256];
    const int t = threadIdx.x;
    s[t] = hist[blockIdx.x * 256 + t];
    __syncthreads();
    #pragma unroll
    for (int off = 128; off > 0; off >>= 1) {
        if (t < off) s[t] += s[t + off];
        __syncthreads();
    }
    if (t == 0) partial[blockIdx.x] = s[0];
}

// scanB: exclusive scan of the 128 partials (one tiny block)
__global__ __launch_bounds__(128) void scan_top(
    const unsigned* __restrict__ partial,
    unsigned* __restrict__ pprefix)
{
    __shared__ unsigned s[128];
    const int t = threadIdx.x;
    s[t] = partial[t];
    __syncthreads();
    #pragma unroll
    for (int off = 1; off < 128; off <<= 1) {
        unsigned x = (t >= off) ? s[t - off] : 0u;
        __syncthreads();
        s[t] += x;
        __syncthreads();
    }
    pprefix[t] = (t > 0) ? s[t - 1] : 0u;   // exclusive
}

// scanC: cursor[b*256+t] = pprefix[b] + exclusive_scan_within_block(hist)
__global__ __launch_bounds__(256) void scan_final(
    const unsigned* __restrict__ hist,
    const unsigned* __restrict__ pprefix,
    unsigned* __restrict__ cursor)
{
    __shared__ unsigned s[256];
    const int t = threadIdx.x;
    const unsigned h = hist[blockIdx.x * 256 + t];
    s[t] = h;
    __syncthreads();
    #pragma unroll
    for (int off = 1; off < 256; off <<= 1) {
        unsigned x = (t >= off) ? s[t - off] : 0u;
        __syncthreads();
        s[t] += x;
        __syncthreads();
    }
    cursor[blockIdx.x * 256 + t] = pprefix[blockIdx.x] + s[t] - h;  // exclusive
}

__global__ __launch_bounds__(256) void bucket_scatter(
    const float* __restrict__ pos,
    const unsigned short* __restrict__ key,
    unsigned* __restrict__ cursor,
    float4* __restrict__ spos4,
    unsigned* __restrict__ s2o)
{
    const int n = blockIdx.x * 256 + threadIdx.x;
    const unsigned k = key[n];
    const unsigned i = atomicAdd(&cursor[k], 1u);
    spos4[i] = make_float4(pos[n * 3 + 0], pos[n * 3 + 1], pos[n * 3 + 2],
                           __uint_as_float((unsigned)n));
    s2o[i] = (unsigned)n;
}

// ---------------------------------------------------------------------------
// Kernel 1: hash-grid encode in SORTED domain, 1 sample/thread, x-pair loads.
// ---------------------------------------------------------------------------
__global__ __launch_bounds__(256) void ngp_encode(
    const float4* __restrict__ spos4,
    const float2* __restrict__ table,
    unsigned* __restrict__ enc,
    Scales sc)
{
    const int bid = blockIdx.x;
    const int l = bid >> 10;                           // block-uniform level
    const int n = ((bid & 1023) << 8) | threadIdx.x;   // sorted-domain index

    const float s = sc.s[l];
    const float2* __restrict__ tl = table + (size_t)l * kT;

    const float4 p4 = spos4[n];
    const float px = (p4.x + 1.0f) * 0.5f;
    const float py = (p4.y + 1.0f) * 0.5f;
    const float pz = (p4.z + 1.0f) * 0.5f;
    const float sx = px * s, sy = py * s, sz = pz * s;
    const float fx = floorf(sx), fy = floorf(sy), fz = floorf(sz);
    const float rx = sx - fx, ry = sy - fy, rz = sz - fz;
    const unsigned cx = (unsigned)fx, cy = (unsigned)fy, cz = (unsigned)fz;

    const unsigned hy0 = cy * 2654435761u, hy1 = (cy + 1u) * 2654435761u;
    const unsigned hz0 = cz * 805459861u,  hz1 = (cz + 1u) * 805459861u;

    float4 pr[4];          // pair loads (both x-corners when cx even)
    float2 ex[4];          // extra loads for odd cx
    unsigned idx0v[4], hyzv[4];

    #pragma unroll
    for (int j = 0; j < 4; ++j) {              // j = oy*2 + oz
        const unsigned hyz = ((j >> 1) ? hy1 : hy0) ^ ((j & 1) ? hz1 : hz0);
        hyzv[j] = hyz;
        const unsigned idx0 = (cx ^ hyz) & kTMask;
        idx0v[j] = idx0;
        pr[j] = *reinterpret_cast<const float4*>(tl + (idx0 & ~1u));
    }

    if (cx & 1u) {
        const unsigned cx1 = cx + 1u;
        #pragma unroll
        for (int j = 0; j < 4; ++j)
            ex[j] = tl[(cx1 ^ hyzv[j]) & kTMask];
    }

    const bool odd = (cx & 1u) != 0u;
    const float wx0 = 1.0f - rx, wx1 = rx;
    float f0 = 0.f, f1 = 0.f;
    #pragma unroll
    for (int j = 0; j < 4; ++j) {
        const float wyz = ((j >> 1) ? ry : 1.0f - ry) *
                          ((j & 1) ? rz : 1.0f - rz);
        const bool hi = (idx0v[j] & 1u) != 0u;
        const float c0x = hi ? pr[j].z : pr[j].x;
        const float c0y = hi ? pr[j].w : pr[j].y;
        const float c1x = odd ? ex[j].x : (hi ? pr[j].x : pr[j].z);
        const float c1y = odd ? ex[j].y : (hi ? pr[j].y : pr[j].w);
        f0 = fmaf(c0x, wx0 * wyz, f0);
        f1 = fmaf(c0y, wx0 * wyz, f1);
        f0 = fmaf(c1x, wx1 * wyz, f0);
        f1 = fmaf(c1y, wx1 * wyz, f1);
    }
    enc[(size_t)l * kN + n] = (unsigned)f2bf(f0) | ((unsigned)f2bf(f1) << 16);
}

// ---------------------------------------------------------------------------
// Kernel 2: fully-fused MLP via MFMA, SORTED domain. 4 waves/block, 64
// samples/wave, wave-private LDS (no __syncthreads). dir gathered and out
// scattered through s2o.
// ---------------------------------------------------------------------------
__global__ __launch_bounds__(256) void ngp_mlp_mfma(
    const unsigned* __restrict__ enc,
    const unsigned short* __restrict__ wbf,
    const float* __restrict__ dir,
    const unsigned* __restrict__ s2o,
    const float* __restrict__ b1, const float* __restrict__ b2,
    const float* __restrict__ b3, const float* __restrict__ b4,
    const float* __restrict__ b5,
    float* __restrict__ out)
{
    __shared__ unsigned short sA[4][4096];   // 64k x 64s per wave
    __shared__ unsigned short sB[4][2048];   // 32k x 64s per wave

    const int tid = threadIdx.x;
    const int wid = tid >> 6;
    const int l   = tid & 63;
    const int cl  = l & 15;
    const int kg  = l >> 4;
    unsigned short* __restrict__ A_ = sA[wid];
    unsigned short* __restrict__ B_ = sB[wid];
    const int gbase = blockIdx.x * 256 + wid * 64;

    // ---- SH-16 for this lane's own sample (dir gathered via s2o) ----
    {
        const unsigned n = s2o[gbase + l];
        const float x = dir[n * 3 + 0], y = dir[n * 3 + 1], z = dir[n * 3 + 2];
        const float xx = x * x, yy = y * y, zz = z * z;
        const float xy = x * y, yz = y * z, xz = x * z;
        float sh[16];
        sh[0] = 0.28209479177387814f;
        sh[1] = -0.48860251190291987f * y;
        sh[2] = 0.48860251190291987f * z;
        sh[3] = -0.48860251190291987f * x;
        sh[4] = 1.0925484305920792f * xy;
        sh[5] = -1.0925484305920792f * yz;
        sh[6] = 0.94617469575755997f * zz - 0.31539156525252005f;
        sh[7] = -1.0925484305920792f * xz;
        sh[8] = 0.54627421529603959f * (xx - yy);
        sh[9] = 0.59004358992664352f * y * (-3.0f * xx + yy);
        sh[10] = 2.8906114426405538f * xy * z;
        sh[11] = 0.45704579946446572f * y * (1.0f - 5.0f * zz);
        sh[12] = 0.3731763325901154f * z * (5.0f * zz - 3.0f);
        sh[13] = 0.45704579946446572f * x * (1.0f - 5.0f * zz);
        sh[14] = 1.445305721320277f * z * (xx - yy);
        sh[15] = 0.59004358992664352f * x * (xx - 3.0f * yy);
        #pragma unroll
        for (int j = 0; j < 16; ++j)
            B_[(l >> 4) * 512 + (16 + j) * 16 + (l & 15)] = f2bf(sh[j]);
    }

    // ---- Layer 1: enc(32) -> h1(64), relu ----
    short8 A1[4];
    #pragma unroll
    for (int m = 0; m < 4; ++m) {
        #pragma unroll
        for (int j = 0; j < 4; ++j) {
            const unsigned v = enc[(size_t)(kg * 4 + j) * kN + (gbase + m * 16 + cl)];
            A1[m][2 * j]     = (short)(v & 0xFFFFu);
            A1[m][2 * j + 1] = (short)(v >> 16);
        }
    }
    {
        short8 B1[4];
        #pragma unroll
        for (int nt = 0; nt < 4; ++nt)
            B1[nt] = *reinterpret_cast<const short8*>(&wbf[(size_t)(nt) * 512 + l * 8]);

        f32x4 acc[4][4];
        #pragma unroll
        for (int nt = 0; nt < 4; ++nt) {
            const float bv = b1[nt * 16 + cl];
            #pragma unroll
            for (int m = 0; m < 4; ++m) {
                acc[m][nt][0] = bv; acc[m][nt][1] = bv; acc[m][nt][2] = bv; acc[m][nt][3] = bv;
            }
        }
        #pragma unroll
        for (int m = 0; m < 4; ++m)
            #pragma unroll
            for (int nt = 0; nt < 4; ++nt)
                acc[m][nt] = __builtin_amdgcn_mfma_f32_16x16x32_bf16(A1[m], B1[nt], acc[m][nt], 0, 0, 0);

        #pragma unroll
        for (int m = 0; m < 4; ++m) {
            #pragma unroll
            for (int nt = 0; nt < 4; ++nt) {
                ushort4v pk;
                #pragma unroll
                for (int r = 0; r < 4; ++r) pk[r] = f2bf(fmaxf(acc[m][nt][r], 0.0f));
                *reinterpret_cast<ushort4v*>(&A_[m * 1024 + (nt * 16 + cl) * 16 + kg * 4]) = pk;
            }
        }
    }

    // ---- Layer 2: h1(64) -> h2(16), no relu; density = exp(h2[0]) ----
    {
        short8 A2[4][2];
        #pragma unroll
        for (int m = 0; m < 4; ++m)
            #pragma unroll
            for (int q = 0; q < 2; ++q)
                #pragma unroll
                for (int e = 0; e < 8; ++e)
                    A2[m][q][e] = (short)A_[m * 1024 + (q * 32 + kg * 8 + e) * 16 + cl];

        short8 B2[2];
        #pragma unroll
        for (int q = 0; q < 2; ++q)
            B2[q] = *reinterpret_cast<const short8*>(&wbf[(size_t)(4 + q) * 512 + l * 8]);

        f32x4 acc[4];
        const float bv = b2[cl];
        #pragma unroll
        for (int m = 0; m < 4; ++m) { acc[m][0] = bv; acc[m][1] = bv; acc[m][2] = bv; acc[m][3] = bv; }
        #pragma unroll
        for (int m = 0; m < 4; ++m)
            #pragma unroll
            for (int q = 0; q < 2; ++q)
                acc[m] = __builtin_amdgcn_mfma_f32_16x16x32_bf16(A2[m][q], B2[q], acc[m], 0, 0, 0);

        #pragma unroll
        for (int m = 0; m < 4; ++m) {
            if (cl == 0) {
                #pragma unroll
                for (int r = 0; r < 4; ++r)
                    out[(size_t)s2o[gbase + m * 16 + kg * 4 + r] * 4 + 0] = expf(acc[m][r]);
            }
            ushort4v pk;
            #pragma unroll
            for (int r = 0; r < 4; ++r) pk[r] = f2bf(acc[m][r]);
            *reinterpret_cast<ushort4v*>(&B_[m * 512 + cl * 16 + kg * 4]) = pk;
        }
    }

    // ---- Layer 3: [h2|SH](32) -> c1(64), relu ----
    {
        short8 A3[4];
        #pragma unroll
        for (int m = 0; m < 4; ++m)
            #pragma unroll
            for (int e = 0; e < 8; ++e)
                A3[m][e] = (short)B_[m * 512 + (kg * 8 + e) * 16 + cl];

        short8 B3[4];
        #pragma unroll
        for (int nt = 0; nt < 4; ++nt)
            B3[nt] = *reinterpret_cast<const short8*>(&wbf[(size_t)(6 + nt) * 512 + l * 8]);

        f32x4 acc[4][4];
        #pragma unroll
        for (int nt = 0; nt < 4; ++nt) {
            const float bv = b3[nt * 16 + cl];
            #pragma unroll
            for (int m = 0; m < 4; ++m) {
                acc[m][nt][0] = bv; acc[m][nt][1] = bv; acc[m][nt][2] = bv; acc[m][nt][3] = bv;
            }
        }
        #pragma unroll
        for (int m = 0; m < 4; ++m)
            #pragma unroll
            for (int nt = 0; nt < 4; ++nt)
                acc[m][nt] = __builtin_amdgcn_mfma_f32_16x16x32_bf16(A3[m], B3[nt], acc[m][nt], 0, 0, 0);

        #pragma unroll
        for (int m = 0; m < 4; ++m) {
            #pragma unroll
            for (int nt = 0; nt < 4; ++nt) {
                ushort4v pk;
                #pragma unroll
                for (int r = 0; r < 4; ++r) pk[r] = f2bf(fmaxf(acc[m][nt][r], 0.0f));
                *reinterpret_cast<ushort4v*>(&A_[m * 1024 + (nt * 16 + cl) * 16 + kg * 4]) = pk;
            }
        }
    }

    // ---- Layer 4: c1(64) -> c2(64), relu ----
    {
        short8 A4[4][2];
        #pragma unroll
        for (int m = 0; m < 4; ++m)
            #pragma unroll
            for (int q = 0; q < 2; ++q)
                #pragma unroll
                for (int e = 0; e < 8; ++e)
                    A4[m][q][e] = (short)A_[m * 1024 + (q * 32 + kg * 8 + e) * 16 + cl];

        short8 B4[2][4];
        #pragma unroll
        for (int q = 0; q < 2; ++q)
            #pragma unroll
            for (int nt = 0; nt < 4; ++nt)
                B4[q][nt] = *reinterpret_cast<const short8*>(&wbf[(size_t)(10 + q * 4 + nt) * 512 + l * 8]);

        f32x4 acc[4][4];
        #pragma unroll
        for (int nt = 0; nt < 4; ++nt) {
            const float bv = b4[nt * 16 + cl];
            #pragma unroll
            for (int m = 0; m < 4; ++m) {
                acc[m][nt][0] = bv; acc[m][nt][1] = bv; acc[m][nt][2] = bv; acc[m][nt][3] = bv;
            }
        }
        #pragma unroll
        for (int m = 0; m < 4; ++m)
            #pragma unroll
            for (int nt = 0; nt < 4; ++nt)
                #pragma unroll
                for (int q = 0; q < 2; ++q)
                    acc[m][nt] = __builtin_amdgcn_mfma_f32_16x16x32_bf16(A4[m][q], B4[q][nt], acc[m][nt], 0, 0, 0);

        #pragma unroll
        for (int m = 0; m < 4; ++m) {
            #pragma unroll
            for (int nt = 0; nt < 4; ++nt) {
                ushort4v pk;
                #pragma unroll
                for (int r = 0; r < 4; ++r) pk[r] = f2bf(fmaxf(acc[m][nt][r], 0.0f));
                *reinterpret_cast<ushort4v*>(&A_[m * 1024 + (nt * 16 + cl) * 16 + kg * 4]) = pk;
            }
        }
    }

    // ---- Layer 5: c2(64) -> 3, sigmoid ----
    {
        short8 A5[4][2];
        #pragma unroll
        for (int m = 0; m < 4; ++m)
            #pragma unroll
            for (int q = 0; q < 2; ++q)
                #pragma unroll
                for (int e = 0; e < 8; ++e)
                    A5[m][q][e] = (short)A_[m * 1024 + (q * 32 + kg * 8 + e) * 16 + cl];

        short8 B5[2];
        #pragma unroll
        for (int q = 0; q < 2; ++q)
            B5[q] = *reinterpret_cast<const short8*>(&wbf[(size_t)(18 + q) * 512 + l * 8]);

        f32x4 acc[4];
        const float bv = (cl < 3) ? b5[cl] : 0.0f;
        #pragma unroll
        for (int m = 0; m < 4; ++m) { acc[m][0] = bv; acc[m][1] = bv; acc[m][2] = bv; acc[m][3] = bv; }
        #pragma unroll
        for (int m = 0; m < 4; ++m)
            #pragma unroll
            for (int q = 0; q < 2; ++q)
                acc[m] = __builtin_amdgcn_mfma_f32_16x16x32_bf16(A5[m][q], B5[q], acc[m], 0, 0, 0);

        if (cl < 3) {
            #pragma unroll
            for (int m = 0; m < 4; ++m)
                #pragma unroll
                for (int r = 0; r < 4; ++r)
                    out[(size_t)s2o[gbase + m * 16 + kg * 4 + r] * 4 + 1 + cl] =
                        1.0f / (1.0f + expf(-acc[m][r]));
        }
    }
}

} // namespace

extern "C" void kernel_launch(void* const* d_in, const int* in_sizes, int n_in,
                              void* d_out, int out_size, void* d_ws, size_t ws_size,
                              hipStream_t stream) {
    (void)in_sizes; (void)n_in; (void)out_size; (void)ws_size;

    Scales sc;
    const double g = exp((log(2048.0) - log(16.0)) / 15.0);
    for (int l = 0; l < kL; ++l) sc.s[l] = (float)floor(16.0 * pow(g, (double)l));

    const float*  pos   = (const float*)d_in[0];
    const float*  dir   = (const float*)d_in[1];
    const float2* table = (const float2*)d_in[2];
    const float *w1 = (const float*)d_in[3],  *b1 = (const float*)d_in[4];
    const float *w2 = (const float*)d_in[5],  *b2 = (const float*)d_in[6];
    const float *w3 = (const float*)d_in[7],  *b3 = (const float*)d_in[8];
    const float *w4 = (const float*)d_in[9],  *b4 = (const float*)d_in[10];
    const float *w5 = (const float*)d_in[11], *b5 = (const float*)d_in[12];
    float* out = (float*)d_out;

    // ws layout (bytes):
    char* ws = (char*)d_ws;
    unsigned short* wbf     = (unsigned short*)(ws);            // 40960 B
    unsigned*       hist    = (unsigned*)(ws + 65536);          // 131072 B
    unsigned*       cursor  = (unsigned*)(ws + 196608);         // 131072 B
    unsigned*       partial = (unsigned*)(ws + 327680);         // 512 B
    unsigned*       pprefix = (unsigned*)(ws + 329728);         // 512 B
    unsigned short* key     = (unsigned short*)(ws + 331776);   // 524288 B
    unsigned*       s2o     = (unsigned*)(ws + 856064);         // 1 MB
    float4*         spos4   = (float4*)(ws + 1966080);          // 4 MB
    unsigned*       enc     = (unsigned*)(ws + 6291456);        // 16.8 MB

    hipMemsetAsync(hist, 0, kB * sizeof(unsigned), stream);
    prep_w<<<40, 256, 0, stream>>>(w1, w2, w3, w4, w5, wbf);
    bucket_hist<<<kN / 256, 256, 0, stream>>>(pos, key, hist);
    scan_partial<<<kB / 256, 256, 0, stream>>>(hist, partial);
    scan_top<<<1, 128, 0, stream>>>(partial, pprefix);
    scan_final<<<kB / 256, 256, 0, stream>>>(hist, pprefix, cursor);
    bucket_scatter<<<kN / 256, 256, 0, stream>>>(pos, key, cursor, spos4, s2o);
    ngp_encode<<<kL * 1024, 256, 0, stream>>>(spos4, table, enc, sc);
    ngp_mlp_mfma<<<kN / 256, 256, 0, stream>>>(enc, wbf, dir, s2o,
        b1, b2, b3, b4, b5, out);
}

// Round 12
// 154.826 us; speedup vs baseline: 1.0843x; 1.0013x over previous
//
#include <hip/hip_runtime.h>
#include <cmath>

namespace {
constexpr int kN = 262144;           // samples (2^18)
constexpr int kL = 16;               // levels
constexpr int kT = 1 << 19;          // hash entries per level (power of 2)
constexpr unsigned kTMask = kT - 1;
constexpr int kB = 32768;            // sort buckets (32^3, Morton)

typedef __attribute__((ext_vector_type(8))) short short8;      // 8 bf16 (A/B frag)
typedef __attribute__((ext_vector_type(4))) float f32x4;       // C/D frag
typedef __attribute__((ext_vector_type(4))) unsigned short ushort4v;

struct Scales { float s[kL]; };

__device__ __forceinline__ unsigned short f2bf(float f) {
    unsigned u = __builtin_bit_cast(unsigned, f);
    return (unsigned short)((u + 0x7FFFu + ((u >> 16) & 1u)) >> 16);  // RNE
}

__device__ __forceinline__ unsigned morton5(unsigned x) {
    x &= 31u;
    x = (x | (x << 8)) & 0x100Fu;
    x = (x | (x << 4)) & 0x10C3u;
    x = (x | (x << 2)) & 0x1249u;
    return x;
}

__device__ __forceinline__ unsigned morton_key(const float* __restrict__ pos, int n) {
    const float px = (pos[n * 3 + 0] + 1.0f) * 0.5f;
    const float py = (pos[n * 3 + 1] + 1.0f) * 0.5f;
    const float pz = (pos[n * 3 + 2] + 1.0f) * 0.5f;
    const unsigned cx = (unsigned)min(31, (int)(px * 32.0f));
    const unsigned cy = (unsigned)min(31, (int)(py * 32.0f));
    const unsigned cz = (unsigned)min(31, (int)(pz * 32.0f));
    return morton5(cx) | (morton5(cy) << 1) | (morton5(cz) << 2);
}

// ---------------------------------------------------------------------------
// Kernel 0: pre-swizzle MLP weights into per-lane MFMA B-fragment order, bf16.
// ---------------------------------------------------------------------------
__global__ __launch_bounds__(256) void prep_w(
    const float* __restrict__ w1, const float* __restrict__ w2,
    const float* __restrict__ w3, const float* __restrict__ w4,
    const float* __restrict__ w5, unsigned short* __restrict__ out)
{
    const int i = blockIdx.x * 256 + threadIdx.x;   // 0..10239
    const int f = i >> 9;
    const int l = (i >> 3) & 63;
    const int e = i & 7;
    const int cl = l & 15;
    const int kg = l >> 4;
    float v = 0.0f;
    if (f < 4) {                 // w1: [32][64]
        v = w1[(kg * 8 + e) * 64 + f * 16 + cl];
    } else if (f < 6) {          // w2: [64][16]
        const int q = f - 4;
        v = w2[(q * 32 + kg * 8 + e) * 16 + cl];
    } else if (f < 10) {         // w3: [32][64]
        v = w3[(kg * 8 + e) * 64 + (f - 6) * 16 + cl];
    } else if (f < 18) {         // w4: [64][64]
        const int g = f - 10, q = g >> 2, nt = g & 3;
        v = w4[(q * 32 + kg * 8 + e) * 64 + nt * 16 + cl];
    } else {                     // w5: [64][3] padded to 16 cols
        const int q = f - 18;
        v = (cl < 3) ? w5[(q * 32 + kg * 8 + e) * 3 + cl] : 0.0f;
    }
    out[i] = f2bf(v);
}

// ---------------------------------------------------------------------------
// Spatial bucketing: counting sort by 32^3 Morton cell.
// R11 post-mortem: hist+scatter were LATENCY-bound on dependent atomic chains
// (~42 cy/atomic observed). Fix: 4 samples/thread -> 4 independent atomic
// chains in flight per lane. key buffer dropped (scatter recomputes Morton).
// ---------------------------------------------------------------------------
__global__ __launch_bounds__(256) void bucket_hist(
    const float* __restrict__ pos,
    unsigned* __restrict__ hist)
{
    const int base = blockIdx.x * 1024 + threadIdx.x;
    #pragma unroll
    for (int t = 0; t < 4; ++t) {
        const int n = base + t * 256;
        atomicAdd(&hist[morton_key(pos, n)], 1u);
    }
}

// scanA: partial[b] = sum of hist[b*256 .. b*256+255]  (coalesced)
__global__ __launch_bounds__(256) void scan_partial(
    const unsigned* __restrict__ hist,
    unsigned* __restrict__ partial)
{
    __shared__ unsigned s[256];
    const int t = threadIdx.x;
    s[t] = hist[blockIdx.x * 256 + t];
    __syncthreads();
    #pragma unroll
    for (int off = 128; off > 0; off >>= 1) {
        if (t < off) s[t] += s[t + off];
        __syncthreads();
    }
    if (t == 0) partial[blockIdx.x] = s[0];
}

// scanB: exclusive scan of the 128 partials (one tiny block)
__global__ __launch_bounds__(128) void scan_top(
    const unsigned* __restrict__ partial,
    unsigned* __restrict__ pprefix)
{
    __shared__ unsigned s[128];
    const int t = threadIdx.x;
    s[t] = partial[t];
    __syncthreads();
    #pragma unroll
    for (int off = 1; off < 128; off <<= 1) {
        unsigned x = (t >= off) ? s[t - off] : 0u;
        __syncthreads();
        s[t] += x;
        __syncthreads();
    }
    pprefix[t] = (t > 0) ? s[t - 1] : 0u;   // exclusive
}

// scanC: cursor[b*256+t] = pprefix[b] + exclusive_scan_within_block(hist)
__global__ __launch_bounds__(256) void scan_final(
    const unsigned* __restrict__ hist,
    const unsigned* __restrict__ pprefix,
    unsigned* __restrict__ cursor)
{
    __shared__ unsigned s[256];
    const int t = threadIdx.x;
    const unsigned h = hist[blockIdx.x * 256 + t];
    s[t] = h;
    __syncthreads();
    #pragma unroll
    for (int off = 1; off < 256; off <<= 1) {
        unsigned x = (t >= off) ? s[t - off] : 0u;
        __syncthreads();
        s[t] += x;
        __syncthreads();
    }
    cursor[blockIdx.x * 256 + t] = pprefix[blockIdx.x] + s[t] - h;  // exclusive
}

__global__ __launch_bounds__(256) void bucket_scatter(
    const float* __restrict__ pos,
    unsigned* __restrict__ cursor,
    float4* __restrict__ spos4,
    unsigned* __restrict__ s2o)
{
    const int base = blockIdx.x * 1024 + threadIdx.x;
    // 4 independent atomic->store chains in flight per lane
    unsigned k[4], i[4];
    #pragma unroll
    for (int t = 0; t < 4; ++t) k[t] = morton_key(pos, base + t * 256);
    #pragma unroll
    for (int t = 0; t < 4; ++t) i[t] = atomicAdd(&cursor[k[t]], 1u);
    #pragma unroll
    for (int t = 0; t < 4; ++t) {
        const int n = base + t * 256;
        spos4[i[t]] = make_float4(pos[n * 3 + 0], pos[n * 3 + 1], pos[n * 3 + 2], 0.0f);
        s2o[i[t]] = (unsigned)n;
    }
}

// ---------------------------------------------------------------------------
// Kernel 1: hash-grid encode in SORTED domain, 1 sample/thread, x-pair loads.
// ---------------------------------------------------------------------------
__global__ __launch_bounds__(256) void ngp_encode(
    const float4* __restrict__ spos4,
    const float2* __restrict__ table,
    unsigned* __restrict__ enc,
    Scales sc)
{
    const int bid = blockIdx.x;
    const int l = bid >> 10;                           // block-uniform level
    const int n = ((bid & 1023) << 8) | threadIdx.x;   // sorted-domain index

    const float s = sc.s[l];
    const float2* __restrict__ tl = table + (size_t)l * kT;

    const float4 p4 = spos4[n];
    const float px = (p4.x + 1.0f) * 0.5f;
    const float py = (p4.y + 1.0f) * 0.5f;
    const float pz = (p4.z + 1.0f) * 0.5f;
    const float sx = px * s, sy = py * s, sz = pz * s;
    const float fx = floorf(sx), fy = floorf(sy), fz = floorf(sz);
    const float rx = sx - fx, ry = sy - fy, rz = sz - fz;
    const unsigned cx = (unsigned)fx, cy = (unsigned)fy, cz = (unsigned)fz;

    const unsigned hy0 = cy * 2654435761u, hy1 = (cy + 1u) * 2654435761u;
    const unsigned hz0 = cz * 805459861u,  hz1 = (cz + 1u) * 805459861u;

    float4 pr[4];          // pair loads (both x-corners when cx even)
    float2 ex[4];          // extra loads for odd cx
    unsigned idx0v[4], hyzv[4];

    #pragma unroll
    for (int j = 0; j < 4; ++j) {              // j = oy*2 + oz
        const unsigned hyz = ((j >> 1) ? hy1 : hy0) ^ ((j & 1) ? hz1 : hz0);
        hyzv[j] = hyz;
        const unsigned idx0 = (cx ^ hyz) & kTMask;
        idx0v[j] = idx0;
        pr[j] = *reinterpret_cast<const float4*>(tl + (idx0 & ~1u));
    }

    if (cx & 1u) {
        const unsigned cx1 = cx + 1u;
        #pragma unroll
        for (int j = 0; j < 4; ++j)
            ex[j] = tl[(cx1 ^ hyzv[j]) & kTMask];
    }

    const bool odd = (cx & 1u) != 0u;
    const float wx0 = 1.0f - rx, wx1 = rx;
    float f0 = 0.f, f1 = 0.f;
    #pragma unroll
    for (int j = 0; j < 4; ++j) {
        const float wyz = ((j >> 1) ? ry : 1.0f - ry) *
                          ((j & 1) ? rz : 1.0f - rz);
        const bool hi = (idx0v[j] & 1u) != 0u;
        const float c0x = hi ? pr[j].z : pr[j].x;
        const float c0y = hi ? pr[j].w : pr[j].y;
        const float c1x = odd ? ex[j].x : (hi ? pr[j].x : pr[j].z);
        const float c1y = odd ? ex[j].y : (hi ? pr[j].y : pr[j].w);
        f0 = fmaf(c0x, wx0 * wyz, f0);
        f1 = fmaf(c0y, wx0 * wyz, f1);
        f0 = fmaf(c1x, wx1 * wyz, f0);
        f1 = fmaf(c1y, wx1 * wyz, f1);
    }
    enc[(size_t)l * kN + n] = (unsigned)f2bf(f0) | ((unsigned)f2bf(f1) << 16);
}

// ---------------------------------------------------------------------------
// Kernel 2: fully-fused MLP via MFMA, SORTED domain. 4 waves/block, 64
// samples/wave, wave-private LDS (no __syncthreads). dir gathered and out
// scattered through s2o.
// ---------------------------------------------------------------------------
__global__ __launch_bounds__(256) void ngp_mlp_mfma(
    const unsigned* __restrict__ enc,
    const unsigned short* __restrict__ wbf,
    const float* __restrict__ dir,
    const unsigned* __restrict__ s2o,
    const float* __restrict__ b1, const float* __restrict__ b2,
    const float* __restrict__ b3, const float* __restrict__ b4,
    const float* __restrict__ b5,
    float* __restrict__ out)
{
    __shared__ unsigned short sA[4][4096];   // 64k x 64s per wave
    __shared__ unsigned short sB[4][2048];   // 32k x 64s per wave

    const int tid = threadIdx.x;
    const int wid = tid >> 6;
    const int l   = tid & 63;
    const int cl  = l & 15;
    const int kg  = l >> 4;
    unsigned short* __restrict__ A_ = sA[wid];
    unsigned short* __restrict__ B_ = sB[wid];
    const int gbase = blockIdx.x * 256 + wid * 64;

    // ---- SH-16 for this lane's own sample (dir gathered via s2o) ----
    {
        const unsigned n = s2o[gbase + l];
        const float x = dir[n * 3 + 0], y = dir[n * 3 + 1], z = dir[n * 3 + 2];
        const float xx = x * x, yy = y * y, zz = z * z;
        const float xy = x * y, yz = y * z, xz = x * z;
        float sh[16];
        sh[0] = 0.28209479177387814f;
        sh[1] = -0.48860251190291987f * y;
        sh[2] = 0.48860251190291987f * z;
        sh[3] = -0.48860251190291987f * x;
        sh[4] = 1.0925484305920792f * xy;
        sh[5] = -1.0925484305920792f * yz;
        sh[6] = 0.94617469575755997f * zz - 0.31539156525252005f;
        sh[7] = -1.0925484305920792f * xz;
        sh[8] = 0.54627421529603959f * (xx - yy);
        sh[9] = 0.59004358992664352f * y * (-3.0f * xx + yy);
        sh[10] = 2.8906114426405538f * xy * z;
        sh[11] = 0.45704579946446572f * y * (1.0f - 5.0f * zz);
        sh[12] = 0.3731763325901154f * z * (5.0f * zz - 3.0f);
        sh[13] = 0.45704579946446572f * x * (1.0f - 5.0f * zz);
        sh[14] = 1.445305721320277f * z * (xx - yy);
        sh[15] = 0.59004358992664352f * x * (xx - 3.0f * yy);
        #pragma unroll
        for (int j = 0; j < 16; ++j)
            B_[(l >> 4) * 512 + (16 + j) * 16 + (l & 15)] = f2bf(sh[j]);
    }

    // ---- Layer 1: enc(32) -> h1(64), relu ----
    short8 A1[4];
    #pragma unroll
    for (int m = 0; m < 4; ++m) {
        #pragma unroll
        for (int j = 0; j < 4; ++j) {
            const unsigned v = enc[(size_t)(kg * 4 + j) * kN + (gbase + m * 16 + cl)];
            A1[m][2 * j]     = (short)(v & 0xFFFFu);
            A1[m][2 * j + 1] = (short)(v >> 16);
        }
    }
    {
        short8 B1[4];
        #pragma unroll
        for (int nt = 0; nt < 4; ++nt)
            B1[nt] = *reinterpret_cast<const short8*>(&wbf[(size_t)(nt) * 512 + l * 8]);

        f32x4 acc[4][4];
        #pragma unroll
        for (int nt = 0; nt < 4; ++nt) {
            const float bv = b1[nt * 16 + cl];
            #pragma unroll
            for (int m = 0; m < 4; ++m) {
                acc[m][nt][0] = bv; acc[m][nt][1] = bv; acc[m][nt][2] = bv; acc[m][nt][3] = bv;
            }
        }
        #pragma unroll
        for (int m = 0; m < 4; ++m)
            #pragma unroll
            for (int nt = 0; nt < 4; ++nt)
                acc[m][nt] = __builtin_amdgcn_mfma_f32_16x16x32_bf16(A1[m], B1[nt], acc[m][nt], 0, 0, 0);

        #pragma unroll
        for (int m = 0; m < 4; ++m) {
            #pragma unroll
            for (int nt = 0; nt < 4; ++nt) {
                ushort4v pk;
                #pragma unroll
                for (int r = 0; r < 4; ++r) pk[r] = f2bf(fmaxf(acc[m][nt][r], 0.0f));
                *reinterpret_cast<ushort4v*>(&A_[m * 1024 + (nt * 16 + cl) * 16 + kg * 4]) = pk;
            }
        }
    }

    // ---- Layer 2: h1(64) -> h2(16), no relu; density = exp(h2[0]) ----
    {
        short8 A2[4][2];
        #pragma unroll
        for (int m = 0; m < 4; ++m)
            #pragma unroll
            for (int q = 0; q < 2; ++q)
                #pragma unroll
                for (int e = 0; e < 8; ++e)
                    A2[m][q][e] = (short)A_[m * 1024 + (q * 32 + kg * 8 + e) * 16 + cl];

        short8 B2[2];
        #pragma unroll
        for (int q = 0; q < 2; ++q)
            B2[q] = *reinterpret_cast<const short8*>(&wbf[(size_t)(4 + q) * 512 + l * 8]);

        f32x4 acc[4];
        const float bv = b2[cl];
        #pragma unroll
        for (int m = 0; m < 4; ++m) { acc[m][0] = bv; acc[m][1] = bv; acc[m][2] = bv; acc[m][3] = bv; }
        #pragma unroll
        for (int m = 0; m < 4; ++m)
            #pragma unroll
            for (int q = 0; q < 2; ++q)
                acc[m] = __builtin_amdgcn_mfma_f32_16x16x32_bf16(A2[m][q], B2[q], acc[m], 0, 0, 0);

        #pragma unroll
        for (int m = 0; m < 4; ++m) {
            if (cl == 0) {
                #pragma unroll
                for (int r = 0; r < 4; ++r)
                    out[(size_t)s2o[gbase + m * 16 + kg * 4 + r] * 4 + 0] = expf(acc[m][r]);
            }
            ushort4v pk;
            #pragma unroll
            for (int r = 0; r < 4; ++r) pk[r] = f2bf(acc[m][r]);
            *reinterpret_cast<ushort4v*>(&B_[m * 512 + cl * 16 + kg * 4]) = pk;
        }
    }

    // ---- Layer 3: [h2|SH](32) -> c1(64), relu ----
    {
        short8 A3[4];
        #pragma unroll
        for (int m = 0; m < 4; ++m)
            #pragma unroll
            for (int e = 0; e < 8; ++e)
                A3[m][e] = (short)B_[m * 512 + (kg * 8 + e) * 16 + cl];

        short8 B3[4];
        #pragma unroll
        for (int nt = 0; nt < 4; ++nt)
            B3[nt] = *reinterpret_cast<const short8*>(&wbf[(size_t)(6 + nt) * 512 + l * 8]);

        f32x4 acc[4][4];
        #pragma unroll
        for (int nt = 0; nt < 4; ++nt) {
            const float bv = b3[nt * 16 + cl];
            #pragma unroll
            for (int m = 0; m < 4; ++m) {
                acc[m][nt][0] = bv; acc[m][nt][1] = bv; acc[m][nt][2] = bv; acc[m][nt][3] = bv;
            }
        }
        #pragma unroll
        for (int m = 0; m < 4; ++m)
            #pragma unroll
            for (int nt = 0; nt < 4; ++nt)
                acc[m][nt] = __builtin_amdgcn_mfma_f32_16x16x32_bf16(A3[m], B3[nt], acc[m][nt], 0, 0, 0);

        #pragma unroll
        for (int m = 0; m < 4; ++m) {
            #pragma unroll
            for (int nt = 0; nt < 4; ++nt) {
                ushort4v pk;
                #pragma unroll
                for (int r = 0; r < 4; ++r) pk[r] = f2bf(fmaxf(acc[m][nt][r], 0.0f));
                *reinterpret_cast<ushort4v*>(&A_[m * 1024 + (nt * 16 + cl) * 16 + kg * 4]) = pk;
            }
        }
    }

    // ---- Layer 4: c1(64) -> c2(64), relu ----
    {
        short8 A4[4][2];
        #pragma unroll
        for (int m = 0; m < 4; ++m)
            #pragma unroll
            for (int q = 0; q < 2; ++q)
                #pragma unroll
                for (int e = 0; e < 8; ++e)
                    A4[m][q][e] = (short)A_[m * 1024 + (q * 32 + kg * 8 + e) * 16 + cl];

        short8 B4[2][4];
        #pragma unroll
        for (int q = 0; q < 2; ++q)
            #pragma unroll
            for (int nt = 0; nt < 4; ++nt)
                B4[q][nt] = *reinterpret_cast<const short8*>(&wbf[(size_t)(10 + q * 4 + nt) * 512 + l * 8]);

        f32x4 acc[4][4];
        #pragma unroll
        for (int nt = 0; nt < 4; ++nt) {
            const float bv = b4[nt * 16 + cl];
            #pragma unroll
            for (int m = 0; m < 4; ++m) {
                acc[m][nt][0] = bv; acc[m][nt][1] = bv; acc[m][nt][2] = bv; acc[m][nt][3] = bv;
            }
        }
        #pragma unroll
        for (int m = 0; m < 4; ++m)
            #pragma unroll
            for (int nt = 0; nt < 4; ++nt)
                #pragma unroll
                for (int q = 0; q < 2; ++q)
                    acc[m][nt] = __builtin_amdgcn_mfma_f32_16x16x32_bf16(A4[m][q], B4[q][nt], acc[m][nt], 0, 0, 0);

        #pragma unroll
        for (int m = 0; m < 4; ++m) {
            #pragma unroll
            for (int nt = 0; nt < 4; ++nt) {
                ushort4v pk;
                #pragma unroll
                for (int r = 0; r < 4; ++r) pk[r] = f2bf(fmaxf(acc[m][nt][r], 0.0f));
                *reinterpret_cast<ushort4v*>(&A_[m * 1024 + (nt * 16 + cl) * 16 + kg * 4]) = pk;
            }
        }
    }

    // ---- Layer 5: c2(64) -> 3, sigmoid ----
    {
        short8 A5[4][2];
        #pragma unroll
        for (int m = 0; m < 4; ++m)
            #pragma unroll
            for (int q = 0; q < 2; ++q)
                #pragma unroll
                for (int e = 0; e < 8; ++e)
                    A5[m][q][e] = (short)A_[m * 1024 + (q * 32 + kg * 8 + e) * 16 + cl];

        short8 B5[2];
        #pragma unroll
        for (int q = 0; q < 2; ++q)
            B5[q] = *reinterpret_cast<const short8*>(&wbf[(size_t)(18 + q) * 512 + l * 8]);

        f32x4 acc[4];
        const float bv = (cl < 3) ? b5[cl] : 0.0f;
        #pragma unroll
        for (int m = 0; m < 4; ++m) { acc[m][0] = bv; acc[m][1] = bv; acc[m][2] = bv; acc[m][3] = bv; }
        #pragma unroll
        for (int m = 0; m < 4; ++m)
            #pragma unroll
            for (int q = 0; q < 2; ++q)
                acc[m] = __builtin_amdgcn_mfma_f32_16x16x32_bf16(A5[m][q], B5[q], acc[m], 0, 0, 0);

        if (cl < 3) {
            #pragma unroll
            for (int m = 0; m < 4; ++m)
                #pragma unroll
                for (int r = 0; r < 4; ++r)
                    out[(size_t)s2o[gbase + m * 16 + kg * 4 + r] * 4 + 1 + cl] =
                        1.0f / (1.0f + expf(-acc[m][r]));
        }
    }
}

} // namespace

extern "C" void kernel_launch(void* const* d_in, const int* in_sizes, int n_in,
                              void* d_out, int out_size, void* d_ws, size_t ws_size,
                              hipStream_t stream) {
    (void)in_sizes; (void)n_in; (void)out_size; (void)ws_size;

    Scales sc;
    const double g = exp((log(2048.0) - log(16.0)) / 15.0);
    for (int l = 0; l < kL; ++l) sc.s[l] = (float)floor(16.0 * pow(g, (double)l));

    const float*  pos   = (const float*)d_in[0];
    const float*  dir   = (const float*)d_in[1];
    const float2* table = (const float2*)d_in[2];
    const float *w1 = (const float*)d_in[3],  *b1 = (const float*)d_in[4];
    const float *w2 = (const float*)d_in[5],  *b2 = (const float*)d_in[6];
    const float *w3 = (const float*)d_in[7],  *b3 = (const float*)d_in[8];
    const float *w4 = (const float*)d_in[9],  *b4 = (const float*)d_in[10];
    const float *w5 = (const float*)d_in[11], *b5 = (const float*)d_in[12];
    float* out = (float*)d_out;

    // ws layout (bytes):
    char* ws = (char*)d_ws;
    unsigned short* wbf     = (unsigned short*)(ws);            // 40960 B
    unsigned*       hist    = (unsigned*)(ws + 65536);          // 131072 B
    unsigned*       cursor  = (unsigned*)(ws + 196608);         // 131072 B
    unsigned*       partial = (unsigned*)(ws + 327680);         // 512 B
    unsigned*       pprefix = (unsigned*)(ws + 329728);         // 512 B
    unsigned*       s2o     = (unsigned*)(ws + 856064);         // 1 MB
    float4*         spos4   = (float4*)(ws + 1966080);          // 4 MB
    unsigned*       enc     = (unsigned*)(ws + 6291456);        // 16.8 MB

    hipMemsetAsync(hist, 0, kB * sizeof(unsigned), stream);
    prep_w<<<40, 256, 0, stream>>>(w1, w2, w3, w4, w5, wbf);
    bucket_hist<<<kN / 1024, 256, 0, stream>>>(pos, hist);
    scan_partial<<<kB / 256, 256, 0, stream>>>(hist, partial);
    scan_top<<<1, 128, 0, stream>>>(partial, pprefix);
    scan_final<<<kB / 256, 256, 0, stream>>>(hist, pprefix, cursor);
    bucket_scatter<<<kN / 1024, 256, 0, stream>>>(pos, cursor, spos4, s2o);
    ngp_encode<<<kL * 1024, 256, 0, stream>>>(spos4, table, enc, sc);
    ngp_mlp_mfma<<<kN / 256, 256, 0, stream>>>(enc, wbf, dir, s2o,
        b1, b2, b3, b4, b5, out);
}

// Round 13
// 146.187 us; speedup vs baseline: 1.1484x; 1.0591x over previous
//
#include <hip/hip_runtime.h>
#include <cmath>

namespace {
constexpr int kN = 262144;           // samples (2^18)
constexpr int kL = 16;               // levels
constexpr int kT = 1 << 19;          // hash entries per level (power of 2)
constexpr unsigned kTMask = kT - 1;
constexpr int kB = 4096;             // sort buckets (16^3, Morton)
constexpr int kSB = 64;              // sort blocks (4096 samples each)

typedef __attribute__((ext_vector_type(8))) short short8;      // 8 bf16 (A/B frag)
typedef __attribute__((ext_vector_type(4))) float f32x4;       // C/D frag
typedef __attribute__((ext_vector_type(4))) unsigned short ushort4v;

struct Scales { float s[kL]; };

__device__ __forceinline__ unsigned short f2bf(float f) {
    unsigned u = __builtin_bit_cast(unsigned, f);
    return (unsigned short)((u + 0x7FFFu + ((u >> 16) & 1u)) >> 16);  // RNE
}

__device__ __forceinline__ unsigned morton5(unsigned x) {
    x &= 31u;
    x = (x | (x << 8)) & 0x100Fu;
    x = (x | (x << 4)) & 0x10C3u;
    x = (x | (x << 2)) & 0x1249u;
    return x;
}

// 16^3 Morton key (4-bit coords through morton5 -> 12-bit key < 4096)
__device__ __forceinline__ unsigned morton_key16(float x, float y, float z) {
    const float px = (x + 1.0f) * 0.5f;
    const float py = (y + 1.0f) * 0.5f;
    const float pz = (z + 1.0f) * 0.5f;
    const unsigned cx = (unsigned)min(15, (int)(px * 16.0f));
    const unsigned cy = (unsigned)min(15, (int)(py * 16.0f));
    const unsigned cz = (unsigned)min(15, (int)(pz * 16.0f));
    return morton5(cx) | (morton5(cy) << 1) | (morton5(cz) << 2);
}

// ---------------------------------------------------------------------------
// Kernel 0: pre-swizzle MLP weights into per-lane MFMA B-fragment order, bf16.
// ---------------------------------------------------------------------------
__global__ __launch_bounds__(256) void prep_w(
    const float* __restrict__ w1, const float* __restrict__ w2,
    const float* __restrict__ w3, const float* __restrict__ w4,
    const float* __restrict__ w5, unsigned short* __restrict__ out)
{
    const int i = blockIdx.x * 256 + threadIdx.x;   // 0..10239
    const int f = i >> 9;
    const int l = (i >> 3) & 63;
    const int e = i & 7;
    const int cl = l & 15;
    const int kg = l >> 4;
    float v = 0.0f;
    if (f < 4) {                 // w1: [32][64]
        v = w1[(kg * 8 + e) * 64 + f * 16 + cl];
    } else if (f < 6) {          // w2: [64][16]
        const int q = f - 4;
        v = w2[(q * 32 + kg * 8 + e) * 16 + cl];
    } else if (f < 10) {         // w3: [32][64]
        v = w3[(kg * 8 + e) * 64 + (f - 6) * 16 + cl];
    } else if (f < 18) {         // w4: [64][64]
        const int g = f - 10, q = g >> 2, nt = g & 3;
        v = w4[(q * 32 + kg * 8 + e) * 64 + nt * 16 + cl];
    } else {                     // w5: [64][3] padded to 16 cols
        const int q = f - 18;
        v = (cl < 3) ? w5[(q * 32 + kg * 8 + e) * 3 + cl] : 0.0f;
    }
    out[i] = f2bf(v);
}

// ---------------------------------------------------------------------------
// Block-local counting sort (NO device atomics — R12 post-mortem: 524k
// device-scope atomics ran at ~42 cy/atomic device-wide and were ~30us).
// 64 blocks x 1024 threads x 4 samples; 4096-bucket LDS histograms.
// Within-bucket order nondeterministic but per-sample results are grouping-
// invariant, so final output is deterministic.
// ---------------------------------------------------------------------------
__global__ __launch_bounds__(1024) void hist_lds(
    const float* __restrict__ pos,
    unsigned* __restrict__ h2)            // h2[kSB][kB]
{
    __shared__ unsigned lh[kB];
    const int t = threadIdx.x;
    #pragma unroll
    for (int i = 0; i < 4; ++i) lh[t + i * 1024] = 0u;
    __syncthreads();
    const int base = blockIdx.x * 4096;
    #pragma unroll
    for (int i = 0; i < 4; ++i) {
        const int n = base + t + i * 1024;
        atomicAdd(&lh[morton_key16(pos[n * 3 + 0], pos[n * 3 + 1], pos[n * 3 + 2])], 1u);
    }
    __syncthreads();
    #pragma unroll
    for (int i = 0; i < 4; ++i)
        h2[(size_t)blockIdx.x * kB + t + i * 1024] = lh[t + i * 1024];  // direct store
}

// boff[b][k] = sum_{b'<b} h2[b'][k];  total[k] = sum_b h2[b][k]
__global__ __launch_bounds__(256) void boff_k(
    const unsigned* __restrict__ h2,
    unsigned* __restrict__ boff,
    unsigned* __restrict__ total)
{
    const int k = blockIdx.x * 256 + threadIdx.x;   // 16 blocks -> 4096 threads
    unsigned acc = 0;
    #pragma unroll 8
    for (int b = 0; b < kSB; ++b) {
        const unsigned v = h2[(size_t)b * kB + k];  // coalesced across k
        boff[(size_t)b * kB + k] = acc;
        acc += v;
    }
    total[k] = acc;
}

// exclusive scan of total[4096] -> cursor[4096], one block
__global__ __launch_bounds__(1024) void scan4096(
    const unsigned* __restrict__ total,
    unsigned* __restrict__ cursor)
{
    __shared__ unsigned s[1024];
    const int t = threadIdx.x;
    const uint4 v = reinterpret_cast<const uint4*>(total)[t];
    const unsigned sum = v.x + v.y + v.z + v.w;
    s[t] = sum;
    __syncthreads();
    for (int off = 1; off < 1024; off <<= 1) {
        unsigned x = (t >= off) ? s[t - off] : 0u;
        __syncthreads();
        s[t] += x;
        __syncthreads();
    }
    const unsigned base = (t > 0) ? s[t - 1] : 0u;
    uint4 c;
    c.x = base;
    c.y = base + v.x;
    c.z = base + v.x + v.y;
    c.w = base + v.x + v.y + v.z;
    reinterpret_cast<uint4*>(cursor)[t] = c;
}

__global__ __launch_bounds__(1024) void scatter_lds(
    const float* __restrict__ pos,
    const unsigned* __restrict__ boff,
    const unsigned* __restrict__ cursor,
    float4* __restrict__ spos4,
    unsigned* __restrict__ s2o)
{
    __shared__ unsigned lh[kB];
    const int t = threadIdx.x;
    #pragma unroll
    for (int i = 0; i < 4; ++i) lh[t + i * 1024] = 0u;
    __syncthreads();
    const int base = blockIdx.x * 4096;
    const unsigned* __restrict__ bo = boff + (size_t)blockIdx.x * kB;
    #pragma unroll
    for (int i = 0; i < 4; ++i) {
        const int n = base + t + i * 1024;
        const float x = pos[n * 3 + 0], y = pos[n * 3 + 1], z = pos[n * 3 + 2];
        const unsigned k = morton_key16(x, y, z);
        const unsigned r = atomicAdd(&lh[k], 1u);         // LDS atomic: local rank
        const unsigned slot = cursor[k] + bo[k] + r;
        spos4[slot] = make_float4(x, y, z, 0.0f);
        s2o[slot] = (unsigned)n;
    }
}

// ---------------------------------------------------------------------------
// Kernel 1: hash-grid encode in SORTED domain, 1 sample/thread, x-pair loads.
// ---------------------------------------------------------------------------
__global__ __launch_bounds__(256) void ngp_encode(
    const float4* __restrict__ spos4,
    const float2* __restrict__ table,
    unsigned* __restrict__ enc,
    Scales sc)
{
    const int bid = blockIdx.x;
    const int l = bid >> 10;                           // block-uniform level
    const int n = ((bid & 1023) << 8) | threadIdx.x;   // sorted-domain index

    const float s = sc.s[l];
    const float2* __restrict__ tl = table + (size_t)l * kT;

    const float4 p4 = spos4[n];
    const float px = (p4.x + 1.0f) * 0.5f;
    const float py = (p4.y + 1.0f) * 0.5f;
    const float pz = (p4.z + 1.0f) * 0.5f;
    const float sx = px * s, sy = py * s, sz = pz * s;
    const float fx = floorf(sx), fy = floorf(sy), fz = floorf(sz);
    const float rx = sx - fx, ry = sy - fy, rz = sz - fz;
    const unsigned cx = (unsigned)fx, cy = (unsigned)fy, cz = (unsigned)fz;

    const unsigned hy0 = cy * 2654435761u, hy1 = (cy + 1u) * 2654435761u;
    const unsigned hz0 = cz * 805459861u,  hz1 = (cz + 1u) * 805459861u;

    float4 pr[4];          // pair loads (both x-corners when cx even)
    float2 ex[4];          // extra loads for odd cx
    unsigned idx0v[4], hyzv[4];

    #pragma unroll
    for (int j = 0; j < 4; ++j) {              // j = oy*2 + oz
        const unsigned hyz = ((j >> 1) ? hy1 : hy0) ^ ((j & 1) ? hz1 : hz0);
        hyzv[j] = hyz;
        const unsigned idx0 = (cx ^ hyz) & kTMask;
        idx0v[j] = idx0;
        pr[j] = *reinterpret_cast<const float4*>(tl + (idx0 & ~1u));
    }

    if (cx & 1u) {
        const unsigned cx1 = cx + 1u;
        #pragma unroll
        for (int j = 0; j < 4; ++j)
            ex[j] = tl[(cx1 ^ hyzv[j]) & kTMask];
    }

    const bool odd = (cx & 1u) != 0u;
    const float wx0 = 1.0f - rx, wx1 = rx;
    float f0 = 0.f, f1 = 0.f;
    #pragma unroll
    for (int j = 0; j < 4; ++j) {
        const float wyz = ((j >> 1) ? ry : 1.0f - ry) *
                          ((j & 1) ? rz : 1.0f - rz);
        const bool hi = (idx0v[j] & 1u) != 0u;
        const float c0x = hi ? pr[j].z : pr[j].x;
        const float c0y = hi ? pr[j].w : pr[j].y;
        const float c1x = odd ? ex[j].x : (hi ? pr[j].x : pr[j].z);
        const float c1y = odd ? ex[j].y : (hi ? pr[j].y : pr[j].w);
        f0 = fmaf(c0x, wx0 * wyz, f0);
        f1 = fmaf(c0y, wx0 * wyz, f1);
        f0 = fmaf(c1x, wx1 * wyz, f0);
        f1 = fmaf(c1y, wx1 * wyz, f1);
    }
    enc[(size_t)l * kN + n] = (unsigned)f2bf(f0) | ((unsigned)f2bf(f1) << 16);
}

// ---------------------------------------------------------------------------
// Kernel 2: fully-fused MLP via MFMA, SORTED domain. 4 waves/block, 64
// samples/wave, wave-private LDS (no __syncthreads). dir gathered and out
// scattered through s2o.
// ---------------------------------------------------------------------------
__global__ __launch_bounds__(256) void ngp_mlp_mfma(
    const unsigned* __restrict__ enc,
    const unsigned short* __restrict__ wbf,
    const float* __restrict__ dir,
    const unsigned* __restrict__ s2o,
    const float* __restrict__ b1, const float* __restrict__ b2,
    const float* __restrict__ b3, const float* __restrict__ b4,
    const float* __restrict__ b5,
    float* __restrict__ out)
{
    __shared__ unsigned short sA[4][4096];   // 64k x 64s per wave
    __shared__ unsigned short sB[4][2048];   // 32k x 64s per wave

    const int tid = threadIdx.x;
    const int wid = tid >> 6;
    const int l   = tid & 63;
    const int cl  = l & 15;
    const int kg  = l >> 4;
    unsigned short* __restrict__ A_ = sA[wid];
    unsigned short* __restrict__ B_ = sB[wid];
    const int gbase = blockIdx.x * 256 + wid * 64;

    // ---- SH-16 for this lane's own sample (dir gathered via s2o) ----
    {
        const unsigned n = s2o[gbase + l];
        const float x = dir[n * 3 + 0], y = dir[n * 3 + 1], z = dir[n * 3 + 2];
        const float xx = x * x, yy = y * y, zz = z * z;
        const float xy = x * y, yz = y * z, xz = x * z;
        float sh[16];
        sh[0] = 0.28209479177387814f;
        sh[1] = -0.48860251190291987f * y;
        sh[2] = 0.48860251190291987f * z;
        sh[3] = -0.48860251190291987f * x;
        sh[4] = 1.0925484305920792f * xy;
        sh[5] = -1.0925484305920792f * yz;
        sh[6] = 0.94617469575755997f * zz - 0.31539156525252005f;
        sh[7] = -1.0925484305920792f * xz;
        sh[8] = 0.54627421529603959f * (xx - yy);
        sh[9] = 0.59004358992664352f * y * (-3.0f * xx + yy);
        sh[10] = 2.8906114426405538f * xy * z;
        sh[11] = 0.45704579946446572f * y * (1.0f - 5.0f * zz);
        sh[12] = 0.3731763325901154f * z * (5.0f * zz - 3.0f);
        sh[13] = 0.45704579946446572f * x * (1.0f - 5.0f * zz);
        sh[14] = 1.445305721320277f * z * (xx - yy);
        sh[15] = 0.59004358992664352f * x * (xx - 3.0f * yy);
        #pragma unroll
        for (int j = 0; j < 16; ++j)
            B_[(l >> 4) * 512 + (16 + j) * 16 + (l & 15)] = f2bf(sh[j]);
    }

    // ---- Layer 1: enc(32) -> h1(64), relu ----
    short8 A1[4];
    #pragma unroll
    for (int m = 0; m < 4; ++m) {
        #pragma unroll
        for (int j = 0; j < 4; ++j) {
            const unsigned v = enc[(size_t)(kg * 4 + j) * kN + (gbase + m * 16 + cl)];
            A1[m][2 * j]     = (short)(v & 0xFFFFu);
            A1[m][2 * j + 1] = (short)(v >> 16);
        }
    }
    {
        short8 B1[4];
        #pragma unroll
        for (int nt = 0; nt < 4; ++nt)
            B1[nt] = *reinterpret_cast<const short8*>(&wbf[(size_t)(nt) * 512 + l * 8]);

        f32x4 acc[4][4];
        #pragma unroll
        for (int nt = 0; nt < 4; ++nt) {
            const float bv = b1[nt * 16 + cl];
            #pragma unroll
            for (int m = 0; m < 4; ++m) {
                acc[m][nt][0] = bv; acc[m][nt][1] = bv; acc[m][nt][2] = bv; acc[m][nt][3] = bv;
            }
        }
        #pragma unroll
        for (int m = 0; m < 4; ++m)
            #pragma unroll
            for (int nt = 0; nt < 4; ++nt)
                acc[m][nt] = __builtin_amdgcn_mfma_f32_16x16x32_bf16(A1[m], B1[nt], acc[m][nt], 0, 0, 0);

        #pragma unroll
        for (int m = 0; m < 4; ++m) {
            #pragma unroll
            for (int nt = 0; nt < 4; ++nt) {
                ushort4v pk;
                #pragma unroll
                for (int r = 0; r < 4; ++r) pk[r] = f2bf(fmaxf(acc[m][nt][r], 0.0f));
                *reinterpret_cast<ushort4v*>(&A_[m * 1024 + (nt * 16 + cl) * 16 + kg * 4]) = pk;
            }
        }
    }

    // ---- Layer 2: h1(64) -> h2(16), no relu; density = exp(h2[0]) ----
    {
        short8 A2[4][2];
        #pragma unroll
        for (int m = 0; m < 4; ++m)
            #pragma unroll
            for (int q = 0; q < 2; ++q)
                #pragma unroll
                for (int e = 0; e < 8; ++e)
                    A2[m][q][e] = (short)A_[m * 1024 + (q * 32 + kg * 8 + e) * 16 + cl];

        short8 B2[2];
        #pragma unroll
        for (int q = 0; q < 2; ++q)
            B2[q] = *reinterpret_cast<const short8*>(&wbf[(size_t)(4 + q) * 512 + l * 8]);

        f32x4 acc[4];
        const float bv = b2[cl];
        #pragma unroll
        for (int m = 0; m < 4; ++m) { acc[m][0] = bv; acc[m][1] = bv; acc[m][2] = bv; acc[m][3] = bv; }
        #pragma unroll
        for (int m = 0; m < 4; ++m)
            #pragma unroll
            for (int q = 0; q < 2; ++q)
                acc[m] = __builtin_amdgcn_mfma_f32_16x16x32_bf16(A2[m][q], B2[q], acc[m], 0, 0, 0);

        #pragma unroll
        for (int m = 0; m < 4; ++m) {
            if (cl == 0) {
                #pragma unroll
                for (int r = 0; r < 4; ++r)
                    out[(size_t)s2o[gbase + m * 16 + kg * 4 + r] * 4 + 0] = expf(acc[m][r]);
            }
            ushort4v pk;
            #pragma unroll
            for (int r = 0; r < 4; ++r) pk[r] = f2bf(acc[m][r]);
            *reinterpret_cast<ushort4v*>(&B_[m * 512 + cl * 16 + kg * 4]) = pk;
        }
    }

    // ---- Layer 3: [h2|SH](32) -> c1(64), relu ----
    {
        short8 A3[4];
        #pragma unroll
        for (int m = 0; m < 4; ++m)
            #pragma unroll
            for (int e = 0; e < 8; ++e)
                A3[m][e] = (short)B_[m * 512 + (kg * 8 + e) * 16 + cl];

        short8 B3[4];
        #pragma unroll
        for (int nt = 0; nt < 4; ++nt)
            B3[nt] = *reinterpret_cast<const short8*>(&wbf[(size_t)(6 + nt) * 512 + l * 8]);

        f32x4 acc[4][4];
        #pragma unroll
        for (int nt = 0; nt < 4; ++nt) {
            const float bv = b3[nt * 16 + cl];
            #pragma unroll
            for (int m = 0; m < 4; ++m) {
                acc[m][nt][0] = bv; acc[m][nt][1] = bv; acc[m][nt][2] = bv; acc[m][nt][3] = bv;
            }
        }
        #pragma unroll
        for (int m = 0; m < 4; ++m)
            #pragma unroll
            for (int nt = 0; nt < 4; ++nt)
                acc[m][nt] = __builtin_amdgcn_mfma_f32_16x16x32_bf16(A3[m], B3[nt], acc[m][nt], 0, 0, 0);

        #pragma unroll
        for (int m = 0; m < 4; ++m) {
            #pragma unroll
            for (int nt = 0; nt < 4; ++nt) {
                ushort4v pk;
                #pragma unroll
                for (int r = 0; r < 4; ++r) pk[r] = f2bf(fmaxf(acc[m][nt][r], 0.0f));
                *reinterpret_cast<ushort4v*>(&A_[m * 1024 + (nt * 16 + cl) * 16 + kg * 4]) = pk;
            }
        }
    }

    // ---- Layer 4: c1(64) -> c2(64), relu ----
    {
        short8 A4[4][2];
        #pragma unroll
        for (int m = 0; m < 4; ++m)
            #pragma unroll
            for (int q = 0; q < 2; ++q)
                #pragma unroll
                for (int e = 0; e < 8; ++e)
                    A4[m][q][e] = (short)A_[m * 1024 + (q * 32 + kg * 8 + e) * 16 + cl];

        short8 B4[2][4];
        #pragma unroll
        for (int q = 0; q < 2; ++q)
            #pragma unroll
            for (int nt = 0; nt < 4; ++nt)
                B4[q][nt] = *reinterpret_cast<const short8*>(&wbf[(size_t)(10 + q * 4 + nt) * 512 + l * 8]);

        f32x4 acc[4][4];
        #pragma unroll
        for (int nt = 0; nt < 4; ++nt) {
            const float bv = b4[nt * 16 + cl];
            #pragma unroll
            for (int m = 0; m < 4; ++m) {
                acc[m][nt][0] = bv; acc[m][nt][1] = bv; acc[m][nt][2] = bv; acc[m][nt][3] = bv;
            }
        }
        #pragma unroll
        for (int m = 0; m < 4; ++m)
            #pragma unroll
            for (int nt = 0; nt < 4; ++nt)
                #pragma unroll
                for (int q = 0; q < 2; ++q)
                    acc[m][nt] = __builtin_amdgcn_mfma_f32_16x16x32_bf16(A4[m][q], B4[q][nt], acc[m][nt], 0, 0, 0);

        #pragma unroll
        for (int m = 0; m < 4; ++m) {
            #pragma unroll
            for (int nt = 0; nt < 4; ++nt) {
                ushort4v pk;
                #pragma unroll
                for (int r = 0; r < 4; ++r) pk[r] = f2bf(fmaxf(acc[m][nt][r], 0.0f));
                *reinterpret_cast<ushort4v*>(&A_[m * 1024 + (nt * 16 + cl) * 16 + kg * 4]) = pk;
            }
        }
    }

    // ---- Layer 5: c2(64) -> 3, sigmoid ----
    {
        short8 A5[4][2];
        #pragma unroll
        for (int m = 0; m < 4; ++m)
            #pragma unroll
            for (int q = 0; q < 2; ++q)
                #pragma unroll
                for (int e = 0; e < 8; ++e)
                    A5[m][q][e] = (short)A_[m * 1024 + (q * 32 + kg * 8 + e) * 16 + cl];

        short8 B5[2];
        #pragma unroll
        for (int q = 0; q < 2; ++q)
            B5[q] = *reinterpret_cast<const short8*>(&wbf[(size_t)(18 + q) * 512 + l * 8]);

        f32x4 acc[4];
        const float bv = (cl < 3) ? b5[cl] : 0.0f;
        #pragma unroll
        for (int m = 0; m < 4; ++m) { acc[m][0] = bv; acc[m][1] = bv; acc[m][2] = bv; acc[m][3] = bv; }
        #pragma unroll
        for (int m = 0; m < 4; ++m)
            #pragma unroll
            for (int q = 0; q < 2; ++q)
                acc[m] = __builtin_amdgcn_mfma_f32_16x16x32_bf16(A5[m][q], B5[q], acc[m], 0, 0, 0);

        if (cl < 3) {
            #pragma unroll
            for (int m = 0; m < 4; ++m)
                #pragma unroll
                for (int r = 0; r < 4; ++r)
                    out[(size_t)s2o[gbase + m * 16 + kg * 4 + r] * 4 + 1 + cl] =
                        1.0f / (1.0f + expf(-acc[m][r]));
        }
    }
}

} // namespace

extern "C" void kernel_launch(void* const* d_in, const int* in_sizes, int n_in,
                              void* d_out, int out_size, void* d_ws, size_t ws_size,
                              hipStream_t stream) {
    (void)in_sizes; (void)n_in; (void)out_size; (void)ws_size;

    Scales sc;
    const double g = exp((log(2048.0) - log(16.0)) / 15.0);
    for (int l = 0; l < kL; ++l) sc.s[l] = (float)floor(16.0 * pow(g, (double)l));

    const float*  pos   = (const float*)d_in[0];
    const float*  dir   = (const float*)d_in[1];
    const float2* table = (const float2*)d_in[2];
    const float *w1 = (const float*)d_in[3],  *b1 = (const float*)d_in[4];
    const float *w2 = (const float*)d_in[5],  *b2 = (const float*)d_in[6];
    const float *w3 = (const float*)d_in[7],  *b3 = (const float*)d_in[8];
    const float *w4 = (const float*)d_in[9],  *b4 = (const float*)d_in[10];
    const float *w5 = (const float*)d_in[11], *b5 = (const float*)d_in[12];
    float* out = (float*)d_out;

    // ws layout (bytes):
    char* ws = (char*)d_ws;
    unsigned short* wbf    = (unsigned short*)(ws);             // 40960 B
    unsigned*       h2     = (unsigned*)(ws + 65536);           // 64*4096*4 = 1 MB
    unsigned*       boff   = (unsigned*)(ws + 1114112);         // 1 MB
    unsigned*       total  = (unsigned*)(ws + 2162688);         // 16 KB
    unsigned*       cursor = (unsigned*)(ws + 2179072);         // 16 KB
    unsigned*       s2o    = (unsigned*)(ws + 2195456);         // 1 MB
    float4*         spos4  = (float4*)(ws + 3244032);           // 4 MB
    unsigned*       enc    = (unsigned*)(ws + 7438336);         // 16.8 MB

    prep_w<<<40, 256, 0, stream>>>(w1, w2, w3, w4, w5, wbf);
    hist_lds<<<kSB, 1024, 0, stream>>>(pos, h2);
    boff_k<<<kB / 256, 256, 0, stream>>>(h2, boff, total);
    scan4096<<<1, 1024, 0, stream>>>(total, cursor);
    scatter_lds<<<kSB, 1024, 0, stream>>>(pos, boff, cursor, spos4, s2o);
    ngp_encode<<<kL * 1024, 256, 0, stream>>>(spos4, table, enc, sc);
    ngp_mlp_mfma<<<kN / 256, 256, 0, stream>>>(enc, wbf, dir, s2o,
        b1, b2, b3, b4, b5, out);
}